// Round 5
// baseline (594.010 us; speedup 1.0000x reference)
//
#include <hip/hip_runtime.h>
#include <hip/hip_bf16.h>
#include <math.h>

#define NN   16384
#define EE   65536
#define DD   512
#define HH   4
#define FINN 7

typedef __attribute__((ext_vector_type(4))) float  floatx4;
typedef __attribute__((ext_vector_type(8))) float  floatx8;
typedef __attribute__((ext_vector_type(8))) short  shortx8;
typedef __attribute__((ext_vector_type(8))) unsigned short ushortx8;

// ---------------- helpers ----------------
__device__ inline float bf2f(unsigned short u) {
  return __uint_as_float(((unsigned)u) << 16);
}
__device__ inline unsigned short f2bf(float f) {
  unsigned u = __float_as_uint(f);
  unsigned r = (u + 0x7fffu + ((u >> 16) & 1u)) >> 16;
  return (unsigned short)r;
}
__device__ inline float wave_reduce_sum(float v) {
  #pragma unroll
  for (int off = 32; off > 0; off >>= 1) v += __shfl_down(v, off, 64);
  return v;
}
__device__ inline float wave_allreduce_sum(float v) {
  #pragma unroll
  for (int off = 32; off > 0; off >>= 1) v += __shfl_xor(v, off, 64);
  return v;
}
__device__ inline void async16(const unsigned short* g, unsigned short* l) {
  __builtin_amdgcn_global_load_lds(
      (const __attribute__((address_space(1))) void*)g,
      (__attribute__((address_space(3))) void*)l, 16, 0, 0);
}

// ---------------- CSR build ----------------
// r11: fused degree-count + edge_attr mean (one pass over edges)
__global__ void k_edge_prep(const int* __restrict__ dst, const float* __restrict__ eattr,
                            int* __restrict__ cnt, float* __restrict__ macc) {
  int tid = blockIdx.x * blockDim.x + threadIdx.x;
  int stride = gridDim.x * blockDim.x;
  float ax = 0.f, ay = 0.f, az = 0.f, aw = 0.f;
  for (int e = tid; e < EE; e += stride) {
    atomicAdd(&cnt[dst[e]], 1);
    float4 v = ((const float4*)eattr)[e];
    ax += v.x; ay += v.y; az += v.z; aw += v.w;
  }
  ax = wave_reduce_sum(ax); ay = wave_reduce_sum(ay);
  az = wave_reduce_sum(az); aw = wave_reduce_sum(aw);
  if ((threadIdx.x & 63) == 0) {
    atomicAdd(&macc[0], ax); atomicAdd(&macc[1], ay);
    atomicAdd(&macc[2], az); atomicAdd(&macc[3], aw);
  }
}

__global__ void k_scan(const int* __restrict__ cnt, int* __restrict__ offs) {
  __shared__ int sums[256];
  int t = threadIdx.x;
  const int chunk = NN / 256;
  int base = t * chunk;
  int s = 0;
  for (int i = 0; i < chunk; ++i) s += cnt[base + i];
  sums[t] = s;
  __syncthreads();
  for (int off = 1; off < 256; off <<= 1) {
    int v = (t >= off) ? sums[t - off] : 0;
    __syncthreads();
    sums[t] += v;
    __syncthreads();
  }
  int run = (t == 0) ? 0 : sums[t - 1];
  for (int i = 0; i < chunk; ++i) {
    offs[base + i] = run;
    run += cnt[base + i];
  }
  if (t == 255) offs[NN] = run;
}

// k_fill materializes CSR-ordered src ids and edge attrs, removing the
// eids->src->eattr dependent-load levels from every gather kernel.
__global__ void k_fill(const int* __restrict__ dst, const int* __restrict__ src,
                       const float* __restrict__ eattr, const int* __restrict__ offs,
                       int* __restrict__ cursor, int* __restrict__ srcs,
                       float4* __restrict__ ea4) {
  int e = blockIdx.x * 256 + threadIdx.x;
  if (e >= EE) return;
  int d = dst[e];
  int p = offs[d] + atomicAdd(&cursor[d], 1);
  srcs[p] = src[e];
  ea4[p] = ((const float4*)eattr)[e];
}

// ------------- weight transpose+cast: W slice (K x N, ld) f32 -> Wt[N][K] bf16 -------
__global__ void k_transcast(const float* __restrict__ W, int ld,
                            unsigned short* __restrict__ Wt, int K, int N) {
  __shared__ float tile[32][33];
  int bx = blockIdx.x;
  int by = blockIdx.y;
  int tx = threadIdx.x & 31, ty = threadIdx.x >> 5;
  #pragma unroll
  for (int i = 0; i < 32; i += 8)
    tile[ty + i][tx] = W[(size_t)(by * 32 + ty + i) * ld + bx * 32 + tx];
  __syncthreads();
  #pragma unroll
  for (int i = 0; i < 32; i += 8)
    Wt[(size_t)(bx * 32 + ty + i) * K + by * 32 + tx] = f2bf(tile[tx][ty + i]);
}

// ------------- combined GAT bias ----------------
__global__ void k_bcomb(const float* __restrict__ bl, const float* __restrict__ br,
                        float* __restrict__ bc0, float* __restrict__ bc1) {
  int i = blockIdx.x * 256 + threadIdx.x;
  if (i >= 4096) return;
  int b = i >> 11, c = i & 2047;
  float v = (c < 1024) ? bl[b * 1024 + c] : br[b * 1024 + c - 1024];
  (b ? bc1 : bc0)[c] = v;
}

// ---------------- input projection ----------------
__global__ void k_proj(const float* __restrict__ x, const float* __restrict__ W,
                       const float* __restrict__ b, unsigned short* __restrict__ hbf) {
  int gid = blockIdx.x * 256 + threadIdx.x;
  if (gid >= NN * DD) return;
  int n = gid >> 9, d = gid & 511;
  const float* xr = x + n * FINN;
  float acc = b[d];
  #pragma unroll
  for (int k = 0; k < FINN; ++k) acc = fmaf(xr[k], W[k * DD + d], acc);
  hbf[gid] = f2bf(fmaxf(acc, 0.f));
}

// ---------------- bf16 MFMA GEMM with XOR-swizzled LDS + XCD block swizzle ----------
__global__ __launch_bounds__(256) void k_bgemm(
    const unsigned short* __restrict__ A, const unsigned short* __restrict__ Bt,
    const float* __restrict__ bias, void* __restrict__ Cout,
    int M, int Nc, int K, int act, int outbf) {
  __shared__ unsigned short As[128 * 64];
  __shared__ unsigned short Bs[128 * 64];
  const int tid = threadIdx.x;
  const int wv = tid >> 6;
  const int lane = tid & 63;
  // bijective XCD swizzle (nwg % 8 == 0 for all our launches)
  int gx = gridDim.x;
  int nwg = gx * gridDim.y;
  int wg = blockIdx.y * gx + blockIdx.x;
  if ((nwg & 7) == 0) {
    int cpx = nwg >> 3;
    wg = (wg & 7) * cpx + (wg >> 3);
  }
  const int row0 = (wg / gx) * 128;
  const int col0 = (wg % gx) * 128;
  const int wrow = (wv & 1) * 64;
  const int wcol = (wv >> 1) * 64;

  floatx4 acc[4][4];
  #pragma unroll
  for (int r = 0; r < 4; ++r)
    #pragma unroll
    for (int c = 0; c < 4; ++c)
      #pragma unroll
      for (int q = 0; q < 4; ++q) acc[r][c][q] = 0.f;

  const unsigned short* Ab = A + (size_t)row0 * K;
  const unsigned short* Bb = Bt + (size_t)col0 * K;
  const int lrow = lane >> 3;                       // 0..7 within segment
  const int lchunk = (lane & 7) ^ lrow;             // swizzled source k-chunk
  const int lk = lchunk * 8;                        // shorts

  const int frow = lane & 15;
  const int fx = lane >> 4;
  const int fsw = lane & 7;

  for (int k0 = 0; k0 < K; k0 += 64) {
    #pragma unroll
    for (int i = 0; i < 4; ++i) {
      int seg = i * 4 + wv;
      int r = seg * 8 + lrow;
      async16(Ab + (size_t)r * K + k0 + lk, &As[seg * 512]);
      async16(Bb + (size_t)r * K + k0 + lk, &Bs[seg * 512]);
    }
    __syncthreads();
    #pragma unroll
    for (int s = 0; s < 2; ++s) {
      int ch = ((s * 4 + fx) ^ fsw) * 8;
      shortx8 af[4], bfr[4];
      #pragma unroll
      for (int r = 0; r < 4; ++r)
        af[r] = *(const shortx8*)&As[(wrow + r * 16 + frow) * 64 + ch];
      #pragma unroll
      for (int c = 0; c < 4; ++c)
        bfr[c] = *(const shortx8*)&Bs[(wcol + c * 16 + frow) * 64 + ch];
      #pragma unroll
      for (int r = 0; r < 4; ++r)
        #pragma unroll
        for (int c = 0; c < 4; ++c)
          acc[r][c] = __builtin_amdgcn_mfma_f32_16x16x32_bf16(af[r], bfr[c], acc[r][c], 0, 0, 0);
    }
    __syncthreads();
  }

  #pragma unroll
  for (int r = 0; r < 4; ++r) {
    int rowb = row0 + wrow + r * 16 + (lane >> 4) * 4;
    #pragma unroll
    for (int c = 0; c < 4; ++c) {
      int col = col0 + wcol + c * 16 + (lane & 15);
      float bv = bias ? bias[col] : 0.f;
      #pragma unroll
      for (int q = 0; q < 4; ++q) {
        float v = acc[r][c][q] + bv;
        if (act) v = fmaxf(v, 0.f);
        if (outbf)
          ((unsigned short*)Cout)[(size_t)(rowb + q) * Nc + col] = f2bf(v);
        else
          ((float*)Cout)[(size_t)(rowb + q) * Nc + col] = v;
      }
    }
  }
}

// ------------- GINE aggregate (CSR-ordered srcs/ea4, no indirection) --------
__global__ void k_gine_agg(const unsigned short* __restrict__ hbf,
                           const int* __restrict__ srcs, const float4* __restrict__ ea4,
                           const float* __restrict__ geW, const float* __restrict__ geb,
                           const int* __restrict__ offs,
                           unsigned short* __restrict__ gbf) {
  int wave = (blockIdx.x * blockDim.x + threadIdx.x) >> 6;
  int lane = threadIdx.x & 63;
  if (wave >= NN) return;
  int n = wave;
  int cbase = lane * 8;
  floatx8 w0, w1, w2, w3, bb;
  #pragma unroll
  for (int j = 0; j < 8; ++j) {
    bb[j] = geb[cbase + j];
    w0[j] = geW[0 * DD + cbase + j];
    w1[j] = geW[1 * DD + cbase + j];
    w2[j] = geW[2 * DD + cbase + j];
    w3[j] = geW[3 * DD + cbase + j];
  }
  floatx8 acc = {0.f, 0.f, 0.f, 0.f, 0.f, 0.f, 0.f, 0.f};
  int beg = offs[n], end = offs[n + 1];
  int scur = srcs[beg];                    // padded array: srcs[EE] readable
  for (int p = beg; p < end; ++p) {
    int s = scur;
    scur = srcs[p + 1];                    // branchless one-ahead (padded)
    float4 ea = ea4[p];
    ushortx8 hv = *(const ushortx8*)(hbf + (size_t)s * DD + cbase);
    #pragma unroll
    for (int j = 0; j < 8; ++j) {
      float ev = bb[j];
      ev = fmaf(ea.x, w0[j], ev);
      ev = fmaf(ea.y, w1[j], ev);
      ev = fmaf(ea.z, w2[j], ev);
      ev = fmaf(ea.w, w3[j], ev);
      acc[j] += fmaxf(bf2f(hv[j]) + ev, 0.f);
    }
  }
  ushortx8 hn = *(const ushortx8*)(hbf + (size_t)n * DD + cbase);
  ushortx8 o;
  #pragma unroll
  for (int j = 0; j < 8; ++j) o[j] = f2bf(bf2f(hn[j]) + acc[j]);
  *(ushortx8*)(gbf + (size_t)n * DD + cbase) = o;
}

// -------- layer-0 LayerNorm (r11: MLP output now bf16 -> half the read bytes) ----
__global__ void k_ln0(const unsigned short* __restrict__ g, const unsigned short* __restrict__ res,
                      const float* __restrict__ gamma, const float* __restrict__ beta,
                      unsigned short* __restrict__ obf) {
  int wave = (blockIdx.x * blockDim.x + threadIdx.x) >> 6;
  int lane = threadIdx.x & 63;
  if (wave >= NN) return;
  int n = wave;
  int cbase = lane * 8;
  ushortx8 gv = *(const ushortx8*)(g + (size_t)n * DD + cbase);
  ushortx8 rv = *(const ushortx8*)(res + (size_t)n * DD + cbase);
  floatx8 v;
  float s = 0.f, sq = 0.f;
  #pragma unroll
  for (int j = 0; j < 8; ++j) {
    float t = fmaxf(bf2f(gv[j]), 0.f) + bf2f(rv[j]);
    v[j] = t;
    s += t; sq += t * t;
  }
  s = wave_allreduce_sum(s);
  sq = wave_allreduce_sum(sq);
  float mu = s * (1.f / DD);
  float var = sq * (1.f / DD) - mu * mu;
  float rstd = rsqrtf(var + 1e-5f);
  ushortx8 ob;
  #pragma unroll
  for (int j = 0; j < 8; ++j)
    ob[j] = f2bf(fmaf((v[j] - mu) * rstd, gamma[cbase + j], beta[cbase + j]));
  *(ushortx8*)(obf + (size_t)n * DD + cbase) = ob;
}

// ======== fused GATv2 (r11): per-(node,head) waves, CSR srcs/ea4, bf16 Hacc ========
// Gather kernels are bandwidth-bound at ~2.0 TB/s on the random-row pattern
// (R2: +1.5x occupancy -> flat; R4: -bytes -> proportional gain). r11 removes
// streamed bytes: inter-batch accumulator is bf16 (16MB each way vs 32MB f32).
// Block = 256 threads = 4 waves = 2 nodes x 2 heads. Grid = NN/2.
__global__ __launch_bounds__(256) void k_gat_fused(
    const unsigned short* __restrict__ xlr,
    const int* __restrict__ srcs,
    const int* __restrict__ offs, const float4* __restrict__ ea4,
    const float* __restrict__ macc,
    const float* __restrict__ geW /*4x2048*/,
    const float* __restrict__ att /*4x512 (HxC)*/,
    unsigned short* __restrict__ Hacc, unsigned short* __restrict__ Xbf,
    const float* __restrict__ gbias,
    const float* __restrict__ gamma, const float* __restrict__ beta,
    int batch) {
  __shared__ float lsum[2][512];          // head-1 normalized sums, per node-slot
  int wv = threadIdx.x >> 6;              // 0..3
  int lane = threadIdx.x & 63;
  int slot = wv >> 1;                     // node slot in block (0,1)
  int h = wv & 1;                         // head within batch
  int n = blockIdx.x * 2 + slot;
  int c8 = lane * 8;
  int hoff = h * 512;                     // xl/xr slice offset (shorts)
  int hc = (2 * batch + h) * 512 + c8;    // channel base in 2048-wide weights
  const float invE = 1.f / EE;
  float meax = macc[0] * invE, meay = macc[1] * invE;
  float meaz = macc[2] * invE, meaw = macc[3] * invE;
  int beg = offs[n], end = offs[n + 1];

  floatx8 w0, w1, w2, w3, at, xr;
  #pragma unroll
  for (int j = 0; j < 8; ++j) {
    w0[j] = geW[0 * (HH * DD) + hc + j];
    w1[j] = geW[1 * (HH * DD) + hc + j];
    w2[j] = geW[2 * (HH * DD) + hc + j];
    w3[j] = geW[3 * (HH * DD) + hc + j];
    at[j] = att[hc + j];
  }
  {
    ushortx8 rr = *(const ushortx8*)(xlr + (size_t)n * 2048 + 1024 + hoff + c8);
    #pragma unroll
    for (int j = 0; j < 8; ++j) xr[j] = bf2f(rr[j]);
  }

  float l;
  floatx8 acc;
  // ---- self-loop (edge attr = mean) ----
  {
    ushortx8 a = *(const ushortx8*)(xlr + (size_t)n * 2048 + hoff + c8);
    float z = 0.f;
    #pragma unroll
    for (int j = 0; j < 8; ++j) {
      float t = bf2f(a[j]) + xr[j];
      t = fmaf(meax, w0[j], t);
      t = fmaf(meay, w1[j], t);
      t = fmaf(meaz, w2[j], t);
      t = fmaf(meaw, w3[j], t);
      t = (t >= 0.f) ? t : 0.2f * t;
      z = fmaf(t, at[j], z);
    }
    #pragma unroll
    for (int off = 32; off > 0; off >>= 1) z += __shfl_xor(z, off, 64);
    float w = __expf(z);
    l = w;
    #pragma unroll
    for (int j = 0; j < 8; ++j) acc[j] = w * bf2f(a[j]);
  }
  // ---- CSR edges (this head only; branchless one-ahead src) ----
  int scur = srcs[beg];                    // padded: srcs[EE] readable
  for (int p = beg; p < end; ++p) {
    int s = scur;
    scur = srcs[p + 1];
    float4 ea = ea4[p];
    ushortx8 a = *(const ushortx8*)(xlr + (size_t)s * 2048 + hoff + c8);
    float z = 0.f;
    #pragma unroll
    for (int j = 0; j < 8; ++j) {
      float t = bf2f(a[j]) + xr[j];
      t = fmaf(ea.x, w0[j], t);
      t = fmaf(ea.y, w1[j], t);
      t = fmaf(ea.z, w2[j], t);
      t = fmaf(ea.w, w3[j], t);
      t = (t >= 0.f) ? t : 0.2f * t;
      z = fmaf(t, at[j], z);
    }
    #pragma unroll
    for (int off = 32; off > 0; off >>= 1) z += __shfl_xor(z, off, 64);
    float w = __expf(z);
    l += w;
    #pragma unroll
    for (int j = 0; j < 8; ++j) acc[j] = fmaf(w, bf2f(a[j]), acc[j]);
  }

  float inv = 1.f / (l + 1e-16f);
  // head-1 waves publish their normalized sums; head-0 waves combine.
  if (h) {
    #pragma unroll
    for (int j = 0; j < 8; ++j) lsum[slot][c8 + j] = acc[j] * inv;
  }
  __syncthreads();
  if (h) return;

  floatx8 hsum;
  #pragma unroll
  for (int j = 0; j < 8; ++j) hsum[j] = acc[j] * inv + lsum[slot][c8 + j];

  unsigned short* hp = Hacc + (size_t)n * DD + c8;
  if (batch == 0) {
    ushortx8 o;
    #pragma unroll
    for (int j = 0; j < 8; ++j) o[j] = f2bf(hsum[j]);
    *(ushortx8*)hp = o;
    return;
  }
  // batch 1: mean over 4 heads, +bias, relu, +residual, LN, write bf16
  ushortx8 pv = *(const ushortx8*)hp;
  ushortx8 rv = *(const ushortx8*)(Xbf + (size_t)n * DD + c8);
  floatx8 v;
  float s = 0.f, sq = 0.f;
  #pragma unroll
  for (int j = 0; j < 8; ++j) {
    float g = (bf2f(pv[j]) + hsum[j]) * 0.25f + gbias[c8 + j];
    float val = fmaxf(g, 0.f) + bf2f(rv[j]);
    v[j] = val;
    s += val; sq += val * val;
  }
  s = wave_allreduce_sum(s);
  sq = wave_allreduce_sum(sq);
  float mu = s * (1.f / DD);
  float var = sq * (1.f / DD) - mu * mu;
  float rstd = rsqrtf(var + 1e-5f);
  ushortx8 ob;
  #pragma unroll
  for (int j = 0; j < 8; ++j)
    ob[j] = f2bf(fmaf((v[j] - mu) * rstd, gamma[c8 + j], beta[c8 + j]));
  *(ushortx8*)(Xbf + (size_t)n * DD + c8) = ob;
}

// ---------------- GCN aggregate + fused bias/relu/res/LN ----------------
__global__ void k_dinv(const int* __restrict__ cnt, float* __restrict__ dinv) {
  int n = blockIdx.x * 256 + threadIdx.x;
  if (n < NN) dinv[n] = rsqrtf((float)cnt[n] + 1.0f);
}

// precompute dinv[src] in CSR order (removes the per-edge scalar gather)
__global__ void k_dsrc(const int* __restrict__ srcs, const float* __restrict__ dinv,
                       float* __restrict__ dinv_src) {
  int p = blockIdx.x * 256 + threadIdx.x;
  if (p < EE) dinv_src[p] = dinv[srcs[p]];
}

__global__ void k_gcn_ln(const unsigned short* __restrict__ hw, const int* __restrict__ srcs,
                         const int* __restrict__ offs, const float* __restrict__ dinv_src,
                         const float* __restrict__ dinv, const float* __restrict__ bias,
                         const float* __restrict__ gamma, const float* __restrict__ beta,
                         unsigned short* __restrict__ Xbf, float* __restrict__ outf) {
  int wave = (blockIdx.x * blockDim.x + threadIdx.x) >> 6;
  int lane = threadIdx.x & 63;
  if (wave >= NN) return;
  int n = wave;
  int cbase = lane * 8;
  float dn = dinv[n];
  floatx8 acc;
  {
    float wself = dn * dn;
    ushortx8 hv = *(const ushortx8*)(hw + (size_t)n * DD + cbase);
    #pragma unroll
    for (int j = 0; j < 8; ++j) acc[j] = wself * bf2f(hv[j]);
  }
  int beg = offs[n], end = offs[n + 1];
  int scur = srcs[beg];                    // padded
  for (int p = beg; p < end; ++p) {
    int s = scur;
    scur = srcs[p + 1];
    float wgt = dinv_src[p] * dn;
    ushortx8 hv = *(const ushortx8*)(hw + (size_t)s * DD + cbase);
    #pragma unroll
    for (int j = 0; j < 8; ++j) acc[j] = fmaf(wgt, bf2f(hv[j]), acc[j]);
  }
  ushortx8 rv = *(const ushortx8*)(Xbf + (size_t)n * DD + cbase);
  floatx8 v;
  float s = 0.f, sq = 0.f;
  #pragma unroll
  for (int j = 0; j < 8; ++j) {
    float g = acc[j] + bias[cbase + j];
    float t = fmaxf(g, 0.f) + bf2f(rv[j]);
    v[j] = t;
    s += t; sq += t * t;
  }
  s = wave_allreduce_sum(s);
  sq = wave_allreduce_sum(sq);
  float mu = s * (1.f / DD);
  float var = sq * (1.f / DD) - mu * mu;
  float rstd = rsqrtf(var + 1e-5f);
  if (outf) {
    float4* o4 = (float4*)(outf + (size_t)n * DD + cbase);
    float4 oa, ob4;
    oa.x = fmaf((v[0] - mu) * rstd, gamma[cbase + 0], beta[cbase + 0]);
    oa.y = fmaf((v[1] - mu) * rstd, gamma[cbase + 1], beta[cbase + 1]);
    oa.z = fmaf((v[2] - mu) * rstd, gamma[cbase + 2], beta[cbase + 2]);
    oa.w = fmaf((v[3] - mu) * rstd, gamma[cbase + 3], beta[cbase + 3]);
    ob4.x = fmaf((v[4] - mu) * rstd, gamma[cbase + 4], beta[cbase + 4]);
    ob4.y = fmaf((v[5] - mu) * rstd, gamma[cbase + 5], beta[cbase + 5]);
    ob4.z = fmaf((v[6] - mu) * rstd, gamma[cbase + 6], beta[cbase + 6]);
    ob4.w = fmaf((v[7] - mu) * rstd, gamma[cbase + 7], beta[cbase + 7]);
    o4[0] = oa;
    o4[1] = ob4;
  } else {
    ushortx8 ob;
    #pragma unroll
    for (int j = 0; j < 8; ++j)
      ob[j] = f2bf(fmaf((v[j] - mu) * rstd, gamma[cbase + j], beta[cbase + j]));
    *(ushortx8*)(Xbf + (size_t)n * DD + cbase) = ob;
  }
}

// ---------------- host-side launcher ----------------
static void launch_bgemm(const unsigned short* A, const unsigned short* Bt,
                         const float* bias, void* C, int M, int Nc, int K,
                         int act, int outbf, hipStream_t stream) {
  dim3 grid(Nc / 128, M / 128);
  k_bgemm<<<grid, 256, 0, stream>>>(A, Bt, bias, C, M, Nc, K, act, outbf);
}

extern "C" void kernel_launch(void* const* d_in, const int* in_sizes, int n_in,
                              void* d_out, int out_size, void* d_ws, size_t ws_size,
                              hipStream_t stream) {
  const float* x       = (const float*)d_in[0];
  const int*   eidx    = (const int*)d_in[1];
  const float* eattr   = (const float*)d_in[2];
  const float* Wproj   = (const float*)d_in[3];
  const float* bproj   = (const float*)d_in[4];
  const float* geW     = (const float*)d_in[5];
  const float* geb     = (const float*)d_in[6];
  const float* gW1     = (const float*)d_in[7];
  const float* gb1     = (const float*)d_in[8];
  const float* gW2     = (const float*)d_in[9];
  const float* gb2     = (const float*)d_in[10];
  const float* gatWl   = (const float*)d_in[11];
  const float* gatbl   = (const float*)d_in[12];
  const float* gatWr   = (const float*)d_in[13];
  const float* gatbr   = (const float*)d_in[14];
  const float* gateW   = (const float*)d_in[15];
  const float* gatatt  = (const float*)d_in[16];
  const float* gatbias = (const float*)d_in[17];
  const float* gcn1W   = (const float*)d_in[18];
  const float* gcn1b   = (const float*)d_in[19];
  const float* gcn2W   = (const float*)d_in[20];
  const float* gcn2b   = (const float*)d_in[21];
  const float* lgamma  = (const float*)d_in[22];
  const float* lbeta   = (const float*)d_in[23];
  const int* srcArr = eidx;
  const int* dstArr = eidx + EE;

  // ---- workspace carving (~105 MB) ----
  char* p = (char*)d_ws;
  unsigned short* Hacc = (unsigned short*)p; p += (size_t)NN * DD * 2;       // 16MB bf16 accum
  unsigned short* Xbf = (unsigned short*)p; p += (size_t)NN * DD * 2;        // 16MB
  unsigned short* U   = (unsigned short*)p; p += (size_t)NN * 2048 * 2;      // 64MB union
  unsigned short* w1t = (unsigned short*)p; p += (size_t)1024 * 512 * 2;
  unsigned short* w2t = (unsigned short*)p; p += (size_t)512 * 1024 * 2;
  unsigned short* wc0 = (unsigned short*)p; p += (size_t)2048 * 512 * 2;
  unsigned short* wc1 = (unsigned short*)p; p += (size_t)2048 * 512 * 2;
  unsigned short* g1t = (unsigned short*)p; p += (size_t)512 * 512 * 2;
  unsigned short* g2t = (unsigned short*)p; p += (size_t)512 * 512 * 2;
  float4* ea4     = (float4*)p;         p += (size_t)(EE + 4) * 16;      // 1MB (16B aligned)
  float* bc0      = (float*)p;          p += 2048 * 4;
  float* bc1      = (float*)p;          p += 2048 * 4;
  float* macc     = (float*)p;          p += 4 * 4;
  float* dinv     = (float*)p;          p += (size_t)NN * 4;
  float* dinv_src = (float*)p;          p += (size_t)(EE + 16) * 4;
  int*   cnt      = (int*)p;            p += (size_t)NN * 4;
  int*   offs     = (int*)p;            p += (size_t)(NN + 1) * 4 + 12;
  int*   cursor   = (int*)p;            p += (size_t)NN * 4;
  int*   srcs     = (int*)p;            p += (size_t)(EE + 16) * 4;

  unsigned short* Zbf = U;                       // NN x 512 (GINE agg out)
  unsigned short* Ybf = U + (size_t)NN * 512;    // NN x 1024 (MLP mid)
  unsigned short* Gbf = U + (size_t)NN * 1536;   // NN x 512 (MLP out, bf16)
  unsigned short* XLR = U;                       // NN x 2048 (GAT xl|xr, 2 heads)
  unsigned short* hw  = U;                       // NN x 512 (GCN h@W)

  hipMemsetAsync(cnt, 0, NN * sizeof(int), stream);
  hipMemsetAsync(cursor, 0, NN * sizeof(int), stream);
  hipMemsetAsync(macc, 0, 4 * sizeof(float), stream);

  k_edge_prep<<<128, 256, 0, stream>>>(dstArr, eattr, cnt, macc);
  k_scan<<<1, 256, 0, stream>>>(cnt, offs);
  k_fill<<<EE / 256, 256, 0, stream>>>(dstArr, srcArr, eattr, offs, cursor, srcs, ea4);
  k_dinv<<<NN / 256, 256, 0, stream>>>(cnt, dinv);
  k_dsrc<<<EE / 256, 256, 0, stream>>>(srcs, dinv, dinv_src);

  // weight prep
  {
    k_transcast<<<dim3(1024 / 32, 512 / 32), 256, 0, stream>>>(gW1, 1024, w1t, 512, 1024);
    k_transcast<<<dim3(512 / 32, 1024 / 32), 256, 0, stream>>>(gW2, 512, w2t, 1024, 512);
    k_transcast<<<dim3(1024 / 32, 512 / 32), 256, 0, stream>>>(gatWl, 2048, wc0, 512, 1024);
    k_transcast<<<dim3(1024 / 32, 512 / 32), 256, 0, stream>>>(gatWr, 2048, wc0 + (size_t)1024 * 512, 512, 1024);
    k_transcast<<<dim3(1024 / 32, 512 / 32), 256, 0, stream>>>(gatWl + 1024, 2048, wc1, 512, 1024);
    k_transcast<<<dim3(1024 / 32, 512 / 32), 256, 0, stream>>>(gatWr + 1024, 2048, wc1 + (size_t)1024 * 512, 512, 1024);
    k_transcast<<<dim3(512 / 32, 512 / 32), 256, 0, stream>>>(gcn1W, 512, g1t, 512, 512);
    k_transcast<<<dim3(512 / 32, 512 / 32), 256, 0, stream>>>(gcn2W, 512, g2t, 512, 512);
    k_bcomb<<<16, 256, 0, stream>>>(gatbl, gatbr, bc0, bc1);
  }

  // input projection (bf16 only)
  k_proj<<<NN * DD / 256, 256, 0, stream>>>(x, Wproj, bproj, Xbf);

  // ---- layer 0: GINEConv + MLP + LN (MLP out now bf16) ----
  k_gine_agg<<<NN / 4, 256, 0, stream>>>(Xbf, srcs, ea4, geW, geb, offs, Zbf);
  launch_bgemm(Zbf, w1t, gb1, Ybf, NN, 1024, 512, 1, 1, stream);
  launch_bgemm(Ybf, w2t, gb2, Gbf, NN, 512, 1024, 0, 1, stream);
  k_ln0<<<NN / 4, 256, 0, stream>>>(Gbf, Xbf, lgamma, lbeta, Xbf);

  // ---- layer 1: GATv2, two 2-head batches; per-(node,head) waves ----
  for (int b = 0; b < 2; ++b) {
    launch_bgemm(Xbf, b ? wc1 : wc0, b ? bc1 : bc0, XLR, NN, 2048, 512, 0, 1, stream);
    k_gat_fused<<<NN / 2, 256, 0, stream>>>(XLR, srcs, offs, ea4, macc,
                                            gateW, gatatt, Hacc, Xbf, gatbias,
                                            lgamma + DD, lbeta + DD, b);
  }

  // ---- layers 2,3: GCN (aggregate + fused LN) ----
  launch_bgemm(Xbf, g1t, nullptr, hw, NN, 512, 512, 0, 1, stream);
  k_gcn_ln<<<NN / 4, 256, 0, stream>>>(hw, srcs, offs, dinv_src, dinv, gcn1b,
                                       lgamma + 2 * DD, lbeta + 2 * DD, Xbf, nullptr);
  launch_bgemm(Xbf, g2t, nullptr, hw, NN, 512, 512, 0, 1, stream);
  k_gcn_ln<<<NN / 4, 256, 0, stream>>>(hw, srcs, offs, dinv_src, dinv, gcn2b,
                                       lgamma + 3 * DD, lbeta + 3 * DD, Xbf, (float*)d_out);
}

// Round 7
// 570.429 us; speedup vs baseline: 1.0413x; 1.0413x over previous
//
#include <hip/hip_runtime.h>
#include <hip/hip_bf16.h>
#include <math.h>

#define NN   16384
#define EE   65536
#define DD   512
#define HH   4
#define FINN 7

typedef __attribute__((ext_vector_type(4))) float  floatx4;
typedef __attribute__((ext_vector_type(8))) float  floatx8;
typedef __attribute__((ext_vector_type(8))) short  shortx8;
typedef __attribute__((ext_vector_type(8))) unsigned short ushortx8;

// ---------------- helpers ----------------
__device__ inline float bf2f(unsigned short u) {
  return __uint_as_float(((unsigned)u) << 16);
}
__device__ inline unsigned short f2bf(float f) {
  unsigned u = __float_as_uint(f);
  unsigned r = (u + 0x7fffu + ((u >> 16) & 1u)) >> 16;
  return (unsigned short)r;
}
__device__ inline float wave_reduce_sum(float v) {
  #pragma unroll
  for (int off = 32; off > 0; off >>= 1) v += __shfl_down(v, off, 64);
  return v;
}
// r13: wave64 sum via DPP. R6 BUG: used row_shl (sums land in lane 0) with a
// bcast cascade that reads lane 15/31 -> garbage. Correct sequence is row_shr
// 1/2/4/8 (lane i = sum x[i-15..i], so lane 15 of each row = row sum), then
// row_bcast15 (lane31=r0+r1, lane63=r2+r3), row_bcast31 (lane63=total).
// 6 VALU-speed v_add_f32_dpp vs 6 serialized ds_swizzle shuffle stages.
// readlane(63) -> wave-uniform. All-lanes-active contexts only.
__device__ inline float wave_sum_u(float v) {
  v += __int_as_float(__builtin_amdgcn_update_dpp(0, __float_as_int(v), 0x111, 0xf, 0xf, true));
  v += __int_as_float(__builtin_amdgcn_update_dpp(0, __float_as_int(v), 0x112, 0xf, 0xf, true));
  v += __int_as_float(__builtin_amdgcn_update_dpp(0, __float_as_int(v), 0x114, 0xf, 0xf, true));
  v += __int_as_float(__builtin_amdgcn_update_dpp(0, __float_as_int(v), 0x118, 0xf, 0xf, true));
  v += __int_as_float(__builtin_amdgcn_update_dpp(0, __float_as_int(v), 0x142, 0xf, 0xf, true));
  v += __int_as_float(__builtin_amdgcn_update_dpp(0, __float_as_int(v), 0x143, 0xf, 0xf, true));
  return __int_as_float(__builtin_amdgcn_readlane(__float_as_int(v), 63));
}
__device__ inline void async16(const unsigned short* g, unsigned short* l) {
  __builtin_amdgcn_global_load_lds(
      (const __attribute__((address_space(1))) void*)g,
      (__attribute__((address_space(3))) void*)l, 16, 0, 0);
}

// ---------------- CSR build ----------------
// fused degree-count + edge_attr mean (one pass over edges)
__global__ void k_edge_prep(const int* __restrict__ dst, const float* __restrict__ eattr,
                            int* __restrict__ cnt, float* __restrict__ macc) {
  int tid = blockIdx.x * blockDim.x + threadIdx.x;
  int stride = gridDim.x * blockDim.x;
  float ax = 0.f, ay = 0.f, az = 0.f, aw = 0.f;
  for (int e = tid; e < EE; e += stride) {
    atomicAdd(&cnt[dst[e]], 1);
    float4 v = ((const float4*)eattr)[e];
    ax += v.x; ay += v.y; az += v.z; aw += v.w;
  }
  ax = wave_reduce_sum(ax); ay = wave_reduce_sum(ay);
  az = wave_reduce_sum(az); aw = wave_reduce_sum(aw);
  if ((threadIdx.x & 63) == 0) {
    atomicAdd(&macc[0], ax); atomicAdd(&macc[1], ay);
    atomicAdd(&macc[2], az); atomicAdd(&macc[3], aw);
  }
}

// k_scan also emits dinv (folds former k_dinv launch)
__global__ void k_scan(const int* __restrict__ cnt, int* __restrict__ offs,
                       float* __restrict__ dinv) {
  __shared__ int sums[256];
  int t = threadIdx.x;
  const int chunk = NN / 256;
  int base = t * chunk;
  int s = 0;
  for (int i = 0; i < chunk; ++i) {
    int c = cnt[base + i];
    s += c;
    dinv[base + i] = rsqrtf((float)c + 1.0f);
  }
  sums[t] = s;
  __syncthreads();
  for (int off = 1; off < 256; off <<= 1) {
    int v = (t >= off) ? sums[t - off] : 0;
    __syncthreads();
    sums[t] += v;
    __syncthreads();
  }
  int run = (t == 0) ? 0 : sums[t - 1];
  for (int i = 0; i < chunk; ++i) {
    offs[base + i] = run;
    run += cnt[base + i];
  }
  if (t == 255) offs[NN] = run;
}

// k_fill materializes CSR-ordered src ids, edge attrs, and dinv[src]
// (folds former k_dsrc launch; removes all indirection from gather loops).
__global__ void k_fill(const int* __restrict__ dst, const int* __restrict__ src,
                       const float* __restrict__ eattr, const int* __restrict__ offs,
                       const float* __restrict__ dinv,
                       int* __restrict__ cursor, int* __restrict__ srcs,
                       float4* __restrict__ ea4, float* __restrict__ dinv_src) {
  int e = blockIdx.x * 256 + threadIdx.x;
  if (e >= EE) return;
  int d = dst[e];
  int p = offs[d] + atomicAdd(&cursor[d], 1);
  int s = src[e];
  srcs[p] = s;
  ea4[p] = ((const float4*)eattr)[e];
  dinv_src[p] = dinv[s];
}

// ------------- weight transpose+cast: W slice (K x N, ld) f32 -> Wt[N][K] bf16 -------
__global__ void k_transcast(const float* __restrict__ W, int ld,
                            unsigned short* __restrict__ Wt, int K, int N) {
  __shared__ float tile[32][33];
  int bx = blockIdx.x;
  int by = blockIdx.y;
  int tx = threadIdx.x & 31, ty = threadIdx.x >> 5;
  #pragma unroll
  for (int i = 0; i < 32; i += 8)
    tile[ty + i][tx] = W[(size_t)(by * 32 + ty + i) * ld + bx * 32 + tx];
  __syncthreads();
  #pragma unroll
  for (int i = 0; i < 32; i += 8)
    Wt[(size_t)(bx * 32 + ty + i) * K + by * 32 + tx] = f2bf(tile[tx][ty + i]);
}

// ------------- combined GAT bias ----------------
__global__ void k_bcomb(const float* __restrict__ bl, const float* __restrict__ br,
                        float* __restrict__ bc0, float* __restrict__ bc1) {
  int i = blockIdx.x * 256 + threadIdx.x;
  if (i >= 4096) return;
  int b = i >> 11, c = i & 2047;
  float v = (c < 1024) ? bl[b * 1024 + c] : br[b * 1024 + c - 1024];
  (b ? bc1 : bc0)[c] = v;
}

// ---------------- input projection ----------------
__global__ void k_proj(const float* __restrict__ x, const float* __restrict__ W,
                       const float* __restrict__ b, unsigned short* __restrict__ hbf) {
  int gid = blockIdx.x * 256 + threadIdx.x;
  if (gid >= NN * DD) return;
  int n = gid >> 9, d = gid & 511;
  const float* xr = x + n * FINN;
  float acc = b[d];
  #pragma unroll
  for (int k = 0; k < FINN; ++k) acc = fmaf(xr[k], W[k * DD + d], acc);
  hbf[gid] = f2bf(fmaxf(acc, 0.f));
}

// ---------------- bf16 MFMA GEMM with XOR-swizzled LDS + XCD block swizzle ----------
__global__ __launch_bounds__(256) void k_bgemm(
    const unsigned short* __restrict__ A, const unsigned short* __restrict__ Bt,
    const float* __restrict__ bias, void* __restrict__ Cout,
    int M, int Nc, int K, int act, int outbf) {
  __shared__ unsigned short As[128 * 64];
  __shared__ unsigned short Bs[128 * 64];
  const int tid = threadIdx.x;
  const int wv = tid >> 6;
  const int lane = tid & 63;
  // bijective XCD swizzle (nwg % 8 == 0 for all our launches)
  int gx = gridDim.x;
  int nwg = gx * gridDim.y;
  int wg = blockIdx.y * gx + blockIdx.x;
  if ((nwg & 7) == 0) {
    int cpx = nwg >> 3;
    wg = (wg & 7) * cpx + (wg >> 3);
  }
  const int row0 = (wg / gx) * 128;
  const int col0 = (wg % gx) * 128;
  const int wrow = (wv & 1) * 64;
  const int wcol = (wv >> 1) * 64;

  floatx4 acc[4][4];
  #pragma unroll
  for (int r = 0; r < 4; ++r)
    #pragma unroll
    for (int c = 0; c < 4; ++c)
      #pragma unroll
      for (int q = 0; q < 4; ++q) acc[r][c][q] = 0.f;

  const unsigned short* Ab = A + (size_t)row0 * K;
  const unsigned short* Bb = Bt + (size_t)col0 * K;
  const int lrow = lane >> 3;                       // 0..7 within segment
  const int lchunk = (lane & 7) ^ lrow;             // swizzled source k-chunk
  const int lk = lchunk * 8;                        // shorts

  const int frow = lane & 15;
  const int fx = lane >> 4;
  const int fsw = lane & 7;

  for (int k0 = 0; k0 < K; k0 += 64) {
    #pragma unroll
    for (int i = 0; i < 4; ++i) {
      int seg = i * 4 + wv;
      int r = seg * 8 + lrow;
      async16(Ab + (size_t)r * K + k0 + lk, &As[seg * 512]);
      async16(Bb + (size_t)r * K + k0 + lk, &Bs[seg * 512]);
    }
    __syncthreads();
    #pragma unroll
    for (int s = 0; s < 2; ++s) {
      int ch = ((s * 4 + fx) ^ fsw) * 8;
      shortx8 af[4], bfr[4];
      #pragma unroll
      for (int r = 0; r < 4; ++r)
        af[r] = *(const shortx8*)&As[(wrow + r * 16 + frow) * 64 + ch];
      #pragma unroll
      for (int c = 0; c < 4; ++c)
        bfr[c] = *(const shortx8*)&Bs[(wcol + c * 16 + frow) * 64 + ch];
      #pragma unroll
      for (int r = 0; r < 4; ++r)
        #pragma unroll
        for (int c = 0; c < 4; ++c)
          acc[r][c] = __builtin_amdgcn_mfma_f32_16x16x32_bf16(af[r], bfr[c], acc[r][c], 0, 0, 0);
    }
    __syncthreads();
  }

  #pragma unroll
  for (int r = 0; r < 4; ++r) {
    int rowb = row0 + wrow + r * 16 + (lane >> 4) * 4;
    #pragma unroll
    for (int c = 0; c < 4; ++c) {
      int col = col0 + wcol + c * 16 + (lane & 15);
      float bv = bias ? bias[col] : 0.f;
      #pragma unroll
      for (int q = 0; q < 4; ++q) {
        float v = acc[r][c][q] + bv;
        if (act) v = fmaxf(v, 0.f);
        if (outbf)
          ((unsigned short*)Cout)[(size_t)(rowb + q) * Nc + col] = f2bf(v);
        else
          ((float*)Cout)[(size_t)(rowb + q) * Nc + col] = v;
      }
    }
  }
}

// ------------- GINE aggregate (CSR-ordered srcs/ea4, no indirection) --------
__global__ void k_gine_agg(const unsigned short* __restrict__ hbf,
                           const int* __restrict__ srcs, const float4* __restrict__ ea4,
                           const float* __restrict__ geW, const float* __restrict__ geb,
                           const int* __restrict__ offs,
                           unsigned short* __restrict__ gbf) {
  int wave = (blockIdx.x * blockDim.x + threadIdx.x) >> 6;
  int lane = threadIdx.x & 63;
  if (wave >= NN) return;
  int n = wave;
  int cbase = lane * 8;
  floatx8 w0, w1, w2, w3, bb;
  #pragma unroll
  for (int j = 0; j < 8; ++j) {
    bb[j] = geb[cbase + j];
    w0[j] = geW[0 * DD + cbase + j];
    w1[j] = geW[1 * DD + cbase + j];
    w2[j] = geW[2 * DD + cbase + j];
    w3[j] = geW[3 * DD + cbase + j];
  }
  floatx8 acc = {0.f, 0.f, 0.f, 0.f, 0.f, 0.f, 0.f, 0.f};
  int beg = offs[n], end = offs[n + 1];
  int scur = srcs[beg];                    // padded array: srcs[EE] readable
  for (int p = beg; p < end; ++p) {
    int s = scur;
    scur = srcs[p + 1];                    // branchless one-ahead (padded)
    float4 ea = ea4[p];
    ushortx8 hv = *(const ushortx8*)(hbf + (size_t)s * DD + cbase);
    #pragma unroll
    for (int j = 0; j < 8; ++j) {
      float ev = bb[j];
      ev = fmaf(ea.x, w0[j], ev);
      ev = fmaf(ea.y, w1[j], ev);
      ev = fmaf(ea.z, w2[j], ev);
      ev = fmaf(ea.w, w3[j], ev);
      acc[j] += fmaxf(bf2f(hv[j]) + ev, 0.f);
    }
  }
  ushortx8 hn = *(const ushortx8*)(hbf + (size_t)n * DD + cbase);
  ushortx8 o;
  #pragma unroll
  for (int j = 0; j < 8; ++j) o[j] = f2bf(bf2f(hn[j]) + acc[j]);
  *(ushortx8*)(gbf + (size_t)n * DD + cbase) = o;
}

// -------- layer-0 LayerNorm ----------------
__global__ void k_ln0(const unsigned short* __restrict__ g, const unsigned short* __restrict__ res,
                      const float* __restrict__ gamma, const float* __restrict__ beta,
                      unsigned short* __restrict__ obf) {
  int wave = (blockIdx.x * blockDim.x + threadIdx.x) >> 6;
  int lane = threadIdx.x & 63;
  if (wave >= NN) return;
  int n = wave;
  int cbase = lane * 8;
  ushortx8 gv = *(const ushortx8*)(g + (size_t)n * DD + cbase);
  ushortx8 rv = *(const ushortx8*)(res + (size_t)n * DD + cbase);
  floatx8 v;
  float s = 0.f, sq = 0.f;
  #pragma unroll
  for (int j = 0; j < 8; ++j) {
    float t = fmaxf(bf2f(gv[j]), 0.f) + bf2f(rv[j]);
    v[j] = t;
    s += t; sq += t * t;
  }
  s = wave_sum_u(s);
  sq = wave_sum_u(sq);
  float mu = s * (1.f / DD);
  float var = sq * (1.f / DD) - mu * mu;
  float rstd = rsqrtf(var + 1e-5f);
  ushortx8 ob;
  #pragma unroll
  for (int j = 0; j < 8; ++j)
    ob[j] = f2bf(fmaf((v[j] - mu) * rstd, gamma[cbase + j], beta[cbase + j]));
  *(ushortx8*)(obf + (size_t)n * DD + cbase) = ob;
}

// ======== fused GATv2 (r13): per-(node,head) waves, DPP logit reduce ========
// The per-edge critical path was gather + VALU + 6 serialized ds_swizzle
// shuffle stages (~300cy). DPP row_shr/row_bcast reduce runs at VALU speed
// (~20cy) and lands wave-uniform via readlane -> feeds __expf a scalar.
// Block = 256 threads = 4 waves = 2 nodes x 2 heads. Grid = NN/2.
__global__ __launch_bounds__(256) void k_gat_fused(
    const unsigned short* __restrict__ xlr,
    const int* __restrict__ srcs,
    const int* __restrict__ offs, const float4* __restrict__ ea4,
    const float* __restrict__ macc,
    const float* __restrict__ geW /*4x2048*/,
    const float* __restrict__ att /*4x512 (HxC)*/,
    unsigned short* __restrict__ Hacc, unsigned short* __restrict__ Xbf,
    const float* __restrict__ gbias,
    const float* __restrict__ gamma, const float* __restrict__ beta,
    int batch) {
  __shared__ float lsum[2][512];          // head-1 normalized sums, per node-slot
  int wv = threadIdx.x >> 6;              // 0..3
  int lane = threadIdx.x & 63;
  int slot = wv >> 1;                     // node slot in block (0,1)
  int h = wv & 1;                         // head within batch
  int n = blockIdx.x * 2 + slot;
  int c8 = lane * 8;
  int hoff = h * 512;                     // xl/xr slice offset (shorts)
  int hc = (2 * batch + h) * 512 + c8;    // channel base in 2048-wide weights
  const float invE = 1.f / EE;
  float meax = macc[0] * invE, meay = macc[1] * invE;
  float meaz = macc[2] * invE, meaw = macc[3] * invE;
  int beg = offs[n], end = offs[n + 1];

  floatx8 w0, w1, w2, w3, at, xr;
  #pragma unroll
  for (int j = 0; j < 8; ++j) {
    w0[j] = geW[0 * (HH * DD) + hc + j];
    w1[j] = geW[1 * (HH * DD) + hc + j];
    w2[j] = geW[2 * (HH * DD) + hc + j];
    w3[j] = geW[3 * (HH * DD) + hc + j];
    at[j] = att[hc + j];
  }
  {
    ushortx8 rr = *(const ushortx8*)(xlr + (size_t)n * 2048 + 1024 + hoff + c8);
    #pragma unroll
    for (int j = 0; j < 8; ++j) xr[j] = bf2f(rr[j]);
  }

  float l;
  floatx8 acc;
  // ---- self-loop (edge attr = mean) ----
  {
    ushortx8 a = *(const ushortx8*)(xlr + (size_t)n * 2048 + hoff + c8);
    float z = 0.f;
    #pragma unroll
    for (int j = 0; j < 8; ++j) {
      float t = bf2f(a[j]) + xr[j];
      t = fmaf(meax, w0[j], t);
      t = fmaf(meay, w1[j], t);
      t = fmaf(meaz, w2[j], t);
      t = fmaf(meaw, w3[j], t);
      t = (t >= 0.f) ? t : 0.2f * t;
      z = fmaf(t, at[j], z);
    }
    float w = __expf(wave_sum_u(z));
    l = w;
    #pragma unroll
    for (int j = 0; j < 8; ++j) acc[j] = w * bf2f(a[j]);
  }
  // ---- CSR edges (this head only; branchless one-ahead src) ----
  int scur = srcs[beg];                    // padded: srcs[EE] readable
  for (int p = beg; p < end; ++p) {
    int s = scur;
    scur = srcs[p + 1];
    float4 ea = ea4[p];
    ushortx8 a = *(const ushortx8*)(xlr + (size_t)s * 2048 + hoff + c8);
    float z = 0.f;
    #pragma unroll
    for (int j = 0; j < 8; ++j) {
      float t = bf2f(a[j]) + xr[j];
      t = fmaf(ea.x, w0[j], t);
      t = fmaf(ea.y, w1[j], t);
      t = fmaf(ea.z, w2[j], t);
      t = fmaf(ea.w, w3[j], t);
      t = (t >= 0.f) ? t : 0.2f * t;
      z = fmaf(t, at[j], z);
    }
    float w = __expf(wave_sum_u(z));
    l += w;
    #pragma unroll
    for (int j = 0; j < 8; ++j) acc[j] = fmaf(w, bf2f(a[j]), acc[j]);
  }

  float inv = 1.f / (l + 1e-16f);
  // head-1 waves publish their normalized sums; head-0 waves combine.
  if (h) {
    #pragma unroll
    for (int j = 0; j < 8; ++j) lsum[slot][c8 + j] = acc[j] * inv;
  }
  __syncthreads();
  if (h) return;

  floatx8 hsum;
  #pragma unroll
  for (int j = 0; j < 8; ++j) hsum[j] = acc[j] * inv + lsum[slot][c8 + j];

  unsigned short* hp = Hacc + (size_t)n * DD + c8;
  if (batch == 0) {
    ushortx8 o;
    #pragma unroll
    for (int j = 0; j < 8; ++j) o[j] = f2bf(hsum[j]);
    *(ushortx8*)hp = o;
    return;
  }
  // batch 1: mean over 4 heads, +bias, relu, +residual, LN, write bf16
  ushortx8 pv = *(const ushortx8*)hp;
  ushortx8 rv = *(const ushortx8*)(Xbf + (size_t)n * DD + c8);
  floatx8 v;
  float s = 0.f, sq = 0.f;
  #pragma unroll
  for (int j = 0; j < 8; ++j) {
    float g = (bf2f(pv[j]) + hsum[j]) * 0.25f + gbias[c8 + j];
    float val = fmaxf(g, 0.f) + bf2f(rv[j]);
    v[j] = val;
    s += val; sq += val * val;
  }
  s = wave_sum_u(s);
  sq = wave_sum_u(sq);
  float mu = s * (1.f / DD);
  float var = sq * (1.f / DD) - mu * mu;
  float rstd = rsqrtf(var + 1e-5f);
  ushortx8 ob;
  #pragma unroll
  for (int j = 0; j < 8; ++j)
    ob[j] = f2bf(fmaf((v[j] - mu) * rstd, gamma[c8 + j], beta[c8 + j]));
  *(ushortx8*)(Xbf + (size_t)n * DD + c8) = ob;
}

// ---------------- GCN aggregate + fused bias/relu/res/LN ----------------
__global__ void k_gcn_ln(const unsigned short* __restrict__ hw, const int* __restrict__ srcs,
                         const int* __restrict__ offs, const float* __restrict__ dinv_src,
                         const float* __restrict__ dinv, const float* __restrict__ bias,
                         const float* __restrict__ gamma, const float* __restrict__ beta,
                         unsigned short* __restrict__ Xbf, float* __restrict__ outf) {
  int wave = (blockIdx.x * blockDim.x + threadIdx.x) >> 6;
  int lane = threadIdx.x & 63;
  if (wave >= NN) return;
  int n = wave;
  int cbase = lane * 8;
  float dn = dinv[n];
  floatx8 acc;
  {
    float wself = dn * dn;
    ushortx8 hv = *(const ushortx8*)(hw + (size_t)n * DD + cbase);
    #pragma unroll
    for (int j = 0; j < 8; ++j) acc[j] = wself * bf2f(hv[j]);
  }
  int beg = offs[n], end = offs[n + 1];
  int scur = srcs[beg];                    // padded
  for (int p = beg; p < end; ++p) {
    int s = scur;
    scur = srcs[p + 1];
    float wgt = dinv_src[p] * dn;
    ushortx8 hv = *(const ushortx8*)(hw + (size_t)s * DD + cbase);
    #pragma unroll
    for (int j = 0; j < 8; ++j) acc[j] = fmaf(wgt, bf2f(hv[j]), acc[j]);
  }
  ushortx8 rv = *(const ushortx8*)(Xbf + (size_t)n * DD + cbase);
  floatx8 v;
  float s = 0.f, sq = 0.f;
  #pragma unroll
  for (int j = 0; j < 8; ++j) {
    float g = acc[j] + bias[cbase + j];
    float t = fmaxf(g, 0.f) + bf2f(rv[j]);
    v[j] = t;
    s += t; sq += t * t;
  }
  s = wave_sum_u(s);
  sq = wave_sum_u(sq);
  float mu = s * (1.f / DD);
  float var = sq * (1.f / DD) - mu * mu;
  float rstd = rsqrtf(var + 1e-5f);
  if (outf) {
    float4* o4 = (float4*)(outf + (size_t)n * DD + cbase);
    float4 oa, ob4;
    oa.x = fmaf((v[0] - mu) * rstd, gamma[cbase + 0], beta[cbase + 0]);
    oa.y = fmaf((v[1] - mu) * rstd, gamma[cbase + 1], beta[cbase + 1]);
    oa.z = fmaf((v[2] - mu) * rstd, gamma[cbase + 2], beta[cbase + 2]);
    oa.w = fmaf((v[3] - mu) * rstd, gamma[cbase + 3], beta[cbase + 3]);
    ob4.x = fmaf((v[4] - mu) * rstd, gamma[cbase + 4], beta[cbase + 4]);
    ob4.y = fmaf((v[5] - mu) * rstd, gamma[cbase + 5], beta[cbase + 5]);
    ob4.z = fmaf((v[6] - mu) * rstd, gamma[cbase + 6], beta[cbase + 6]);
    ob4.w = fmaf((v[7] - mu) * rstd, gamma[cbase + 7], beta[cbase + 7]);
    o4[0] = oa;
    o4[1] = ob4;
  } else {
    ushortx8 ob;
    #pragma unroll
    for (int j = 0; j < 8; ++j)
      ob[j] = f2bf(fmaf((v[j] - mu) * rstd, gamma[cbase + j], beta[cbase + j]));
    *(ushortx8*)(Xbf + (size_t)n * DD + cbase) = ob;
  }
}

// ---------------- host-side launcher ----------------
static void launch_bgemm(const unsigned short* A, const unsigned short* Bt,
                         const float* bias, void* C, int M, int Nc, int K,
                         int act, int outbf, hipStream_t stream) {
  dim3 grid(Nc / 128, M / 128);
  k_bgemm<<<grid, 256, 0, stream>>>(A, Bt, bias, C, M, Nc, K, act, outbf);
}

extern "C" void kernel_launch(void* const* d_in, const int* in_sizes, int n_in,
                              void* d_out, int out_size, void* d_ws, size_t ws_size,
                              hipStream_t stream) {
  const float* x       = (const float*)d_in[0];
  const int*   eidx    = (const int*)d_in[1];
  const float* eattr   = (const float*)d_in[2];
  const float* Wproj   = (const float*)d_in[3];
  const float* bproj   = (const float*)d_in[4];
  const float* geW     = (const float*)d_in[5];
  const float* geb     = (const float*)d_in[6];
  const float* gW1     = (const float*)d_in[7];
  const float* gb1     = (const float*)d_in[8];
  const float* gW2     = (const float*)d_in[9];
  const float* gb2     = (const float*)d_in[10];
  const float* gatWl   = (const float*)d_in[11];
  const float* gatbl   = (const float*)d_in[12];
  const float* gatWr   = (const float*)d_in[13];
  const float* gatbr   = (const float*)d_in[14];
  const float* gateW   = (const float*)d_in[15];
  const float* gatatt  = (const float*)d_in[16];
  const float* gatbias = (const float*)d_in[17];
  const float* gcn1W   = (const float*)d_in[18];
  const float* gcn1b   = (const float*)d_in[19];
  const float* gcn2W   = (const float*)d_in[20];
  const float* gcn2b   = (const float*)d_in[21];
  const float* lgamma  = (const float*)d_in[22];
  const float* lbeta   = (const float*)d_in[23];
  const int* srcArr = eidx;
  const int* dstArr = eidx + EE;

  // ---- workspace carving (~105 MB) ----
  char* p = (char*)d_ws;
  unsigned short* Hacc = (unsigned short*)p; p += (size_t)NN * DD * 2;       // 16MB bf16 accum
  unsigned short* Xbf = (unsigned short*)p; p += (size_t)NN * DD * 2;        // 16MB
  unsigned short* U   = (unsigned short*)p; p += (size_t)NN * 2048 * 2;      // 64MB union
  unsigned short* w1t = (unsigned short*)p; p += (size_t)1024 * 512 * 2;
  unsigned short* w2t = (unsigned short*)p; p += (size_t)512 * 1024 * 2;
  unsigned short* wc0 = (unsigned short*)p; p += (size_t)2048 * 512 * 2;
  unsigned short* wc1 = (unsigned short*)p; p += (size_t)2048 * 512 * 2;
  unsigned short* g1t = (unsigned short*)p; p += (size_t)512 * 512 * 2;
  unsigned short* g2t = (unsigned short*)p; p += (size_t)512 * 512 * 2;
  float4* ea4     = (float4*)p;         p += (size_t)(EE + 4) * 16;      // 1MB (16B aligned)
  float* bc0      = (float*)p;          p += 2048 * 4;
  float* bc1      = (float*)p;          p += 2048 * 4;
  float* macc     = (float*)p;          p += 4 * 4;
  float* dinv     = (float*)p;          p += (size_t)NN * 4;
  float* dinv_src = (float*)p;          p += (size_t)(EE + 16) * 4;
  int*   cnt      = (int*)p;            p += (size_t)NN * 4;
  int*   offs     = (int*)p;            p += (size_t)(NN + 1) * 4 + 12;
  int*   cursor   = (int*)p;            p += (size_t)NN * 4;
  int*   srcs     = (int*)p;            p += (size_t)(EE + 16) * 4;

  unsigned short* Zbf = U;                       // NN x 512 (GINE agg out)
  unsigned short* Ybf = U + (size_t)NN * 512;    // NN x 1024 (MLP mid)
  unsigned short* Gbf = U + (size_t)NN * 1536;   // NN x 512 (MLP out, bf16)
  unsigned short* XLR = U;                       // NN x 2048 (GAT xl|xr, 2 heads)
  unsigned short* hw  = U;                       // NN x 512 (GCN h@W)

  hipMemsetAsync(cnt, 0, NN * sizeof(int), stream);
  hipMemsetAsync(cursor, 0, NN * sizeof(int), stream);
  hipMemsetAsync(macc, 0, 4 * sizeof(float), stream);

  k_edge_prep<<<128, 256, 0, stream>>>(dstArr, eattr, cnt, macc);
  k_scan<<<1, 256, 0, stream>>>(cnt, offs, dinv);
  k_fill<<<EE / 256, 256, 0, stream>>>(dstArr, srcArr, eattr, offs, dinv,
                                       cursor, srcs, ea4, dinv_src);

  // weight prep
  {
    k_transcast<<<dim3(1024 / 32, 512 / 32), 256, 0, stream>>>(gW1, 1024, w1t, 512, 1024);
    k_transcast<<<dim3(512 / 32, 1024 / 32), 256, 0, stream>>>(gW2, 512, w2t, 1024, 512);
    k_transcast<<<dim3(1024 / 32, 512 / 32), 256, 0, stream>>>(gatWl, 2048, wc0, 512, 1024);
    k_transcast<<<dim3(1024 / 32, 512 / 32), 256, 0, stream>>>(gatWr, 2048, wc0 + (size_t)1024 * 512, 512, 1024);
    k_transcast<<<dim3(1024 / 32, 512 / 32), 256, 0, stream>>>(gatWl + 1024, 2048, wc1, 512, 1024);
    k_transcast<<<dim3(1024 / 32, 512 / 32), 256, 0, stream>>>(gatWr + 1024, 2048, wc1 + (size_t)1024 * 512, 512, 1024);
    k_transcast<<<dim3(512 / 32, 512 / 32), 256, 0, stream>>>(gcn1W, 512, g1t, 512, 512);
    k_transcast<<<dim3(512 / 32, 512 / 32), 256, 0, stream>>>(gcn2W, 512, g2t, 512, 512);
    k_bcomb<<<16, 256, 0, stream>>>(gatbl, gatbr, bc0, bc1);
  }

  // input projection (bf16 only)
  k_proj<<<NN * DD / 256, 256, 0, stream>>>(x, Wproj, bproj, Xbf);

  // ---- layer 0: GINEConv + MLP + LN (MLP out bf16) ----
  k_gine_agg<<<NN / 4, 256, 0, stream>>>(Xbf, srcs, ea4, geW, geb, offs, Zbf);
  launch_bgemm(Zbf, w1t, gb1, Ybf, NN, 1024, 512, 1, 1, stream);
  launch_bgemm(Ybf, w2t, gb2, Gbf, NN, 512, 1024, 0, 1, stream);
  k_ln0<<<NN / 4, 256, 0, stream>>>(Gbf, Xbf, lgamma, lbeta, Xbf);

  // ---- layer 1: GATv2, two 2-head batches; per-(node,head) waves ----
  for (int b = 0; b < 2; ++b) {
    launch_bgemm(Xbf, b ? wc1 : wc0, b ? bc1 : bc0, XLR, NN, 2048, 512, 0, 1, stream);
    k_gat_fused<<<NN / 2, 256, 0, stream>>>(XLR, srcs, offs, ea4, macc,
                                            gateW, gatatt, Hacc, Xbf, gatbias,
                                            lgamma + DD, lbeta + DD, b);
  }

  // ---- layers 2,3: GCN (aggregate + fused LN) ----
  launch_bgemm(Xbf, g1t, nullptr, hw, NN, 512, 512, 0, 1, stream);
  k_gcn_ln<<<NN / 4, 256, 0, stream>>>(hw, srcs, offs, dinv_src, dinv, gcn1b,
                                       lgamma + 2 * DD, lbeta + 2 * DD, Xbf, nullptr);
  launch_bgemm(Xbf, g2t, nullptr, hw, NN, 512, 512, 0, 1, stream);
  k_gcn_ln<<<NN / 4, 256, 0, stream>>>(hw, srcs, offs, dinv_src, dinv, gcn2b,
                                       lgamma + 3 * DD, lbeta + 3 * DD, Xbf, (float*)d_out);
}

// Round 8
// 561.515 us; speedup vs baseline: 1.0579x; 1.0159x over previous
//
#include <hip/hip_runtime.h>
#include <hip/hip_bf16.h>
#include <math.h>

#define NN   16384
#define EE   65536
#define DD   512
#define HH   4
#define FINN 7

typedef __attribute__((ext_vector_type(4))) float  floatx4;
typedef __attribute__((ext_vector_type(8))) float  floatx8;
typedef __attribute__((ext_vector_type(8))) short  shortx8;
typedef __attribute__((ext_vector_type(8))) unsigned short ushortx8;

// ---------------- helpers ----------------
__device__ inline float bf2f(unsigned short u) {
  return __uint_as_float(((unsigned)u) << 16);
}
__device__ inline unsigned short f2bf(float f) {
  unsigned u = __float_as_uint(f);
  unsigned r = (u + 0x7fffu + ((u >> 16) & 1u)) >> 16;
  return (unsigned short)r;
}
__device__ inline float wave_reduce_sum(float v) {
  #pragma unroll
  for (int off = 32; off > 0; off >>= 1) v += __shfl_down(v, off, 64);
  return v;
}
// wave64 sum via DPP: row_shr 1/2/4/8 (lane 15 of each 16-row = row sum),
// row_bcast15 (lane31=r0+r1, lane63=r2+r3), row_bcast31 (lane63=total).
// 6 VALU-speed v_add_f32_dpp vs 6 serialized ds_swizzle shuffle stages.
// readlane(63) -> wave-uniform. All-lanes-active contexts only.
__device__ inline float wave_sum_u(float v) {
  v += __int_as_float(__builtin_amdgcn_update_dpp(0, __float_as_int(v), 0x111, 0xf, 0xf, true));
  v += __int_as_float(__builtin_amdgcn_update_dpp(0, __float_as_int(v), 0x112, 0xf, 0xf, true));
  v += __int_as_float(__builtin_amdgcn_update_dpp(0, __float_as_int(v), 0x114, 0xf, 0xf, true));
  v += __int_as_float(__builtin_amdgcn_update_dpp(0, __float_as_int(v), 0x118, 0xf, 0xf, true));
  v += __int_as_float(__builtin_amdgcn_update_dpp(0, __float_as_int(v), 0x142, 0xf, 0xf, true));
  v += __int_as_float(__builtin_amdgcn_update_dpp(0, __float_as_int(v), 0x143, 0xf, 0xf, true));
  return __int_as_float(__builtin_amdgcn_readlane(__float_as_int(v), 63));
}
__device__ inline void async16(const unsigned short* g, unsigned short* l) {
  __builtin_amdgcn_global_load_lds(
      (const __attribute__((address_space(1))) void*)g,
      (__attribute__((address_space(3))) void*)l, 16, 0, 0);
}

// ---------------- CSR build ----------------
// fused degree-count + edge_attr mean (one pass over edges)
__global__ void k_edge_prep(const int* __restrict__ dst, const float* __restrict__ eattr,
                            int* __restrict__ cnt, float* __restrict__ macc) {
  int tid = blockIdx.x * blockDim.x + threadIdx.x;
  int stride = gridDim.x * blockDim.x;
  float ax = 0.f, ay = 0.f, az = 0.f, aw = 0.f;
  for (int e = tid; e < EE; e += stride) {
    atomicAdd(&cnt[dst[e]], 1);
    float4 v = ((const float4*)eattr)[e];
    ax += v.x; ay += v.y; az += v.z; aw += v.w;
  }
  ax = wave_reduce_sum(ax); ay = wave_reduce_sum(ay);
  az = wave_reduce_sum(az); aw = wave_reduce_sum(aw);
  if ((threadIdx.x & 63) == 0) {
    atomicAdd(&macc[0], ax); atomicAdd(&macc[1], ay);
    atomicAdd(&macc[2], az); atomicAdd(&macc[3], aw);
  }
}

// k_scan also emits dinv (folds former k_dinv launch)
__global__ void k_scan(const int* __restrict__ cnt, int* __restrict__ offs,
                       float* __restrict__ dinv) {
  __shared__ int sums[256];
  int t = threadIdx.x;
  const int chunk = NN / 256;
  int base = t * chunk;
  int s = 0;
  for (int i = 0; i < chunk; ++i) {
    int c = cnt[base + i];
    s += c;
    dinv[base + i] = rsqrtf((float)c + 1.0f);
  }
  sums[t] = s;
  __syncthreads();
  for (int off = 1; off < 256; off <<= 1) {
    int v = (t >= off) ? sums[t - off] : 0;
    __syncthreads();
    sums[t] += v;
    __syncthreads();
  }
  int run = (t == 0) ? 0 : sums[t - 1];
  for (int i = 0; i < chunk; ++i) {
    offs[base + i] = run;
    run += cnt[base + i];
  }
  if (t == 255) offs[NN] = run;
}

// k_fill materializes CSR-ordered src ids, edge attrs, and dinv[src]
// (removes all indirection from gather loops).
__global__ void k_fill(const int* __restrict__ dst, const int* __restrict__ src,
                       const float* __restrict__ eattr, const int* __restrict__ offs,
                       const float* __restrict__ dinv,
                       int* __restrict__ cursor, int* __restrict__ srcs,
                       float4* __restrict__ ea4, float* __restrict__ dinv_src) {
  int e = blockIdx.x * 256 + threadIdx.x;
  if (e >= EE) return;
  int d = dst[e];
  int p = offs[d] + atomicAdd(&cursor[d], 1);
  int s = src[e];
  srcs[p] = s;
  ea4[p] = ((const float4*)eattr)[e];
  dinv_src[p] = dinv[s];
}

// ------------- weight transpose+cast: W slice (K x N, ld) f32 -> Wt[N][K] bf16 -------
__global__ void k_transcast(const float* __restrict__ W, int ld,
                            unsigned short* __restrict__ Wt, int K, int N) {
  __shared__ float tile[32][33];
  int bx = blockIdx.x;
  int by = blockIdx.y;
  int tx = threadIdx.x & 31, ty = threadIdx.x >> 5;
  #pragma unroll
  for (int i = 0; i < 32; i += 8)
    tile[ty + i][tx] = W[(size_t)(by * 32 + ty + i) * ld + bx * 32 + tx];
  __syncthreads();
  #pragma unroll
  for (int i = 0; i < 32; i += 8)
    Wt[(size_t)(bx * 32 + ty + i) * K + by * 32 + tx] = f2bf(tile[tx][ty + i]);
}

// ------------- combined GAT bias ----------------
__global__ void k_bcomb(const float* __restrict__ bl, const float* __restrict__ br,
                        float* __restrict__ bc0, float* __restrict__ bc1) {
  int i = blockIdx.x * 256 + threadIdx.x;
  if (i >= 4096) return;
  int b = i >> 11, c = i & 2047;
  float v = (c < 1024) ? bl[b * 1024 + c] : br[b * 1024 + c - 1024];
  (b ? bc1 : bc0)[c] = v;
}

// ---------------- input projection ----------------
__global__ void k_proj(const float* __restrict__ x, const float* __restrict__ W,
                       const float* __restrict__ b, unsigned short* __restrict__ hbf) {
  int gid = blockIdx.x * 256 + threadIdx.x;
  if (gid >= NN * DD) return;
  int n = gid >> 9, d = gid & 511;
  const float* xr = x + n * FINN;
  float acc = b[d];
  #pragma unroll
  for (int k = 0; k < FINN; ++k) acc = fmaf(xr[k], W[k * DD + d], acc);
  hbf[gid] = f2bf(fmaxf(acc, 0.f));
}

// ---------------- bf16 MFMA GEMM, XOR-swizzled LDS, XCD swizzle --------------------
// r14: LDS-staged coalesced epilogue. The old C-write was 64 scalar 2-byte
// stores/thread (32B segments/wave) — ~25-30% of kernel time at K=512 where
// only 8 K-iters amortize it. Now: stage the 128x128 bf16 C tile in the
// (dead after K-loop) A/B staging LDS, barrier, then 8 fully-coalesced
// global_store_dwordx4 per thread (1KB/wave-instr). All outputs bf16.
__global__ __launch_bounds__(256) void k_bgemm(
    const unsigned short* __restrict__ A, const unsigned short* __restrict__ Bt,
    const float* __restrict__ bias, unsigned short* __restrict__ Cout,
    int M, int Nc, int K, int act) {
  __shared__ unsigned short S[16384];   // 32KB: A(8192) | B(8192), then C tile
  unsigned short* As = S;
  unsigned short* Bs = S + 8192;
  const int tid = threadIdx.x;
  const int wv = tid >> 6;
  const int lane = tid & 63;
  // bijective XCD swizzle (nwg % 8 == 0 for all our launches)
  int gx = gridDim.x;
  int nwg = gx * gridDim.y;
  int wg = blockIdx.y * gx + blockIdx.x;
  if ((nwg & 7) == 0) {
    int cpx = nwg >> 3;
    wg = (wg & 7) * cpx + (wg >> 3);
  }
  const int row0 = (wg / gx) * 128;
  const int col0 = (wg % gx) * 128;
  const int wrow = (wv & 1) * 64;
  const int wcol = (wv >> 1) * 64;

  floatx4 acc[4][4];
  #pragma unroll
  for (int r = 0; r < 4; ++r)
    #pragma unroll
    for (int c = 0; c < 4; ++c)
      #pragma unroll
      for (int q = 0; q < 4; ++q) acc[r][c][q] = 0.f;

  const unsigned short* Ab = A + (size_t)row0 * K;
  const unsigned short* Bb = Bt + (size_t)col0 * K;
  const int lrow = lane >> 3;                       // 0..7 within segment
  const int lchunk = (lane & 7) ^ lrow;             // swizzled source k-chunk
  const int lk = lchunk * 8;                        // shorts

  const int frow = lane & 15;
  const int fx = lane >> 4;
  const int fsw = lane & 7;

  for (int k0 = 0; k0 < K; k0 += 64) {
    #pragma unroll
    for (int i = 0; i < 4; ++i) {
      int seg = i * 4 + wv;
      int r = seg * 8 + lrow;
      async16(Ab + (size_t)r * K + k0 + lk, &As[seg * 512]);
      async16(Bb + (size_t)r * K + k0 + lk, &Bs[seg * 512]);
    }
    __syncthreads();
    #pragma unroll
    for (int s = 0; s < 2; ++s) {
      int ch = ((s * 4 + fx) ^ fsw) * 8;
      shortx8 af[4], bfr[4];
      #pragma unroll
      for (int r = 0; r < 4; ++r)
        af[r] = *(const shortx8*)&As[(wrow + r * 16 + frow) * 64 + ch];
      #pragma unroll
      for (int c = 0; c < 4; ++c)
        bfr[c] = *(const shortx8*)&Bs[(wcol + c * 16 + frow) * 64 + ch];
      #pragma unroll
      for (int r = 0; r < 4; ++r)
        #pragma unroll
        for (int c = 0; c < 4; ++c)
          acc[r][c] = __builtin_amdgcn_mfma_f32_16x16x32_bf16(af[r], bfr[c], acc[r][c], 0, 0, 0);
    }
    __syncthreads();
  }

  // ---- epilogue: bias/act, stage bf16 C tile in LDS, coalesced store ----
  #pragma unroll
  for (int r = 0; r < 4; ++r) {
    int lr0 = wrow + r * 16 + (lane >> 4) * 4;       // local row base
    #pragma unroll
    for (int c = 0; c < 4; ++c) {
      int lc = wcol + c * 16 + (lane & 15);          // local col
      float bv = bias ? bias[col0 + lc] : 0.f;
      #pragma unroll
      for (int q = 0; q < 4; ++q) {
        float v = acc[r][c][q] + bv;
        if (act) v = fmaxf(v, 0.f);
        S[(lr0 + q) * 128 + lc] = f2bf(v);
      }
    }
  }
  __syncthreads();
  #pragma unroll
  for (int i = 0; i < 8; ++i) {
    int idx = (i * 256 + tid) * 8;                   // short index in tile
    int lr = idx >> 7;
    int lc = idx & 127;
    *(ushortx8*)(Cout + (size_t)(row0 + lr) * Nc + col0 + lc) =
        *(const ushortx8*)&S[idx];
  }
}

// ------------- GINE aggregate (CSR-ordered srcs/ea4, no indirection) --------
__global__ void k_gine_agg(const unsigned short* __restrict__ hbf,
                           const int* __restrict__ srcs, const float4* __restrict__ ea4,
                           const float* __restrict__ geW, const float* __restrict__ geb,
                           const int* __restrict__ offs,
                           unsigned short* __restrict__ gbf) {
  int wave = (blockIdx.x * blockDim.x + threadIdx.x) >> 6;
  int lane = threadIdx.x & 63;
  if (wave >= NN) return;
  int n = wave;
  int cbase = lane * 8;
  floatx8 w0, w1, w2, w3, bb;
  #pragma unroll
  for (int j = 0; j < 8; ++j) {
    bb[j] = geb[cbase + j];
    w0[j] = geW[0 * DD + cbase + j];
    w1[j] = geW[1 * DD + cbase + j];
    w2[j] = geW[2 * DD + cbase + j];
    w3[j] = geW[3 * DD + cbase + j];
  }
  floatx8 acc = {0.f, 0.f, 0.f, 0.f, 0.f, 0.f, 0.f, 0.f};
  int beg = offs[n], end = offs[n + 1];
  int scur = srcs[beg];                    // padded array: srcs[EE] readable
  for (int p = beg; p < end; ++p) {
    int s = scur;
    scur = srcs[p + 1];                    // branchless one-ahead (padded)
    float4 ea = ea4[p];
    ushortx8 hv = *(const ushortx8*)(hbf + (size_t)s * DD + cbase);
    #pragma unroll
    for (int j = 0; j < 8; ++j) {
      float ev = bb[j];
      ev = fmaf(ea.x, w0[j], ev);
      ev = fmaf(ea.y, w1[j], ev);
      ev = fmaf(ea.z, w2[j], ev);
      ev = fmaf(ea.w, w3[j], ev);
      acc[j] += fmaxf(bf2f(hv[j]) + ev, 0.f);
    }
  }
  ushortx8 hn = *(const ushortx8*)(hbf + (size_t)n * DD + cbase);
  ushortx8 o;
  #pragma unroll
  for (int j = 0; j < 8; ++j) o[j] = f2bf(bf2f(hn[j]) + acc[j]);
  *(ushortx8*)(gbf + (size_t)n * DD + cbase) = o;
}

// -------- layer-0 LayerNorm ----------------
__global__ void k_ln0(const unsigned short* __restrict__ g, const unsigned short* __restrict__ res,
                      const float* __restrict__ gamma, const float* __restrict__ beta,
                      unsigned short* __restrict__ obf) {
  int wave = (blockIdx.x * blockDim.x + threadIdx.x) >> 6;
  int lane = threadIdx.x & 63;
  if (wave >= NN) return;
  int n = wave;
  int cbase = lane * 8;
  ushortx8 gv = *(const ushortx8*)(g + (size_t)n * DD + cbase);
  ushortx8 rv = *(const ushortx8*)(res + (size_t)n * DD + cbase);
  floatx8 v;
  float s = 0.f, sq = 0.f;
  #pragma unroll
  for (int j = 0; j < 8; ++j) {
    float t = fmaxf(bf2f(gv[j]), 0.f) + bf2f(rv[j]);
    v[j] = t;
    s += t; sq += t * t;
  }
  s = wave_sum_u(s);
  sq = wave_sum_u(sq);
  float mu = s * (1.f / DD);
  float var = sq * (1.f / DD) - mu * mu;
  float rstd = rsqrtf(var + 1e-5f);
  ushortx8 ob;
  #pragma unroll
  for (int j = 0; j < 8; ++j)
    ob[j] = f2bf(fmaf((v[j] - mu) * rstd, gamma[cbase + j], beta[cbase + j]));
  *(ushortx8*)(obf + (size_t)n * DD + cbase) = ob;
}

// ======== fused GATv2: per-(node,head) waves, DPP logit reduce ========
// Block = 256 threads = 4 waves = 2 nodes x 2 heads. Grid = NN/2.
__global__ __launch_bounds__(256) void k_gat_fused(
    const unsigned short* __restrict__ xlr,
    const int* __restrict__ srcs,
    const int* __restrict__ offs, const float4* __restrict__ ea4,
    const float* __restrict__ macc,
    const float* __restrict__ geW /*4x2048*/,
    const float* __restrict__ att /*4x512 (HxC)*/,
    unsigned short* __restrict__ Hacc, unsigned short* __restrict__ Xbf,
    const float* __restrict__ gbias,
    const float* __restrict__ gamma, const float* __restrict__ beta,
    int batch) {
  __shared__ float lsum[2][512];          // head-1 normalized sums, per node-slot
  int wv = threadIdx.x >> 6;              // 0..3
  int lane = threadIdx.x & 63;
  int slot = wv >> 1;                     // node slot in block (0,1)
  int h = wv & 1;                         // head within batch
  int n = blockIdx.x * 2 + slot;
  int c8 = lane * 8;
  int hoff = h * 512;                     // xl/xr slice offset (shorts)
  int hc = (2 * batch + h) * 512 + c8;    // channel base in 2048-wide weights
  const float invE = 1.f / EE;
  float meax = macc[0] * invE, meay = macc[1] * invE;
  float meaz = macc[2] * invE, meaw = macc[3] * invE;
  int beg = offs[n], end = offs[n + 1];

  floatx8 w0, w1, w2, w3, at, xr;
  #pragma unroll
  for (int j = 0; j < 8; ++j) {
    w0[j] = geW[0 * (HH * DD) + hc + j];
    w1[j] = geW[1 * (HH * DD) + hc + j];
    w2[j] = geW[2 * (HH * DD) + hc + j];
    w3[j] = geW[3 * (HH * DD) + hc + j];
    at[j] = att[hc + j];
  }
  {
    ushortx8 rr = *(const ushortx8*)(xlr + (size_t)n * 2048 + 1024 + hoff + c8);
    #pragma unroll
    for (int j = 0; j < 8; ++j) xr[j] = bf2f(rr[j]);
  }

  float l;
  floatx8 acc;
  // ---- self-loop (edge attr = mean) ----
  {
    ushortx8 a = *(const ushortx8*)(xlr + (size_t)n * 2048 + hoff + c8);
    float z = 0.f;
    #pragma unroll
    for (int j = 0; j < 8; ++j) {
      float t = bf2f(a[j]) + xr[j];
      t = fmaf(meax, w0[j], t);
      t = fmaf(meay, w1[j], t);
      t = fmaf(meaz, w2[j], t);
      t = fmaf(meaw, w3[j], t);
      t = (t >= 0.f) ? t : 0.2f * t;
      z = fmaf(t, at[j], z);
    }
    float w = __expf(wave_sum_u(z));
    l = w;
    #pragma unroll
    for (int j = 0; j < 8; ++j) acc[j] = w * bf2f(a[j]);
  }
  // ---- CSR edges (this head only; branchless one-ahead src) ----
  int scur = srcs[beg];                    // padded: srcs[EE] readable
  for (int p = beg; p < end; ++p) {
    int s = scur;
    scur = srcs[p + 1];
    float4 ea = ea4[p];
    ushortx8 a = *(const ushortx8*)(xlr + (size_t)s * 2048 + hoff + c8);
    float z = 0.f;
    #pragma unroll
    for (int j = 0; j < 8; ++j) {
      float t = bf2f(a[j]) + xr[j];
      t = fmaf(ea.x, w0[j], t);
      t = fmaf(ea.y, w1[j], t);
      t = fmaf(ea.z, w2[j], t);
      t = fmaf(ea.w, w3[j], t);
      t = (t >= 0.f) ? t : 0.2f * t;
      z = fmaf(t, at[j], z);
    }
    float w = __expf(wave_sum_u(z));
    l += w;
    #pragma unroll
    for (int j = 0; j < 8; ++j) acc[j] = fmaf(w, bf2f(a[j]), acc[j]);
  }

  float inv = 1.f / (l + 1e-16f);
  // head-1 waves publish their normalized sums; head-0 waves combine.
  if (h) {
    #pragma unroll
    for (int j = 0; j < 8; ++j) lsum[slot][c8 + j] = acc[j] * inv;
  }
  __syncthreads();
  if (h) return;

  floatx8 hsum;
  #pragma unroll
  for (int j = 0; j < 8; ++j) hsum[j] = acc[j] * inv + lsum[slot][c8 + j];

  unsigned short* hp = Hacc + (size_t)n * DD + c8;
  if (batch == 0) {
    ushortx8 o;
    #pragma unroll
    for (int j = 0; j < 8; ++j) o[j] = f2bf(hsum[j]);
    *(ushortx8*)hp = o;
    return;
  }
  // batch 1: mean over 4 heads, +bias, relu, +residual, LN, write bf16
  ushortx8 pv = *(const ushortx8*)hp;
  ushortx8 rv = *(const ushortx8*)(Xbf + (size_t)n * DD + c8);
  floatx8 v;
  float s = 0.f, sq = 0.f;
  #pragma unroll
  for (int j = 0; j < 8; ++j) {
    float g = (bf2f(pv[j]) + hsum[j]) * 0.25f + gbias[c8 + j];
    float val = fmaxf(g, 0.f) + bf2f(rv[j]);
    v[j] = val;
    s += val; sq += val * val;
  }
  s = wave_sum_u(s);
  sq = wave_sum_u(sq);
  float mu = s * (1.f / DD);
  float var = sq * (1.f / DD) - mu * mu;
  float rstd = rsqrtf(var + 1e-5f);
  ushortx8 ob;
  #pragma unroll
  for (int j = 0; j < 8; ++j)
    ob[j] = f2bf(fmaf((v[j] - mu) * rstd, gamma[c8 + j], beta[c8 + j]));
  *(ushortx8*)(Xbf + (size_t)n * DD + c8) = ob;
}

// ---------------- GCN aggregate + fused bias/relu/res/LN ----------------
__global__ void k_gcn_ln(const unsigned short* __restrict__ hw, const int* __restrict__ srcs,
                         const int* __restrict__ offs, const float* __restrict__ dinv_src,
                         const float* __restrict__ dinv, const float* __restrict__ bias,
                         const float* __restrict__ gamma, const float* __restrict__ beta,
                         unsigned short* __restrict__ Xbf, float* __restrict__ outf) {
  int wave = (blockIdx.x * blockDim.x + threadIdx.x) >> 6;
  int lane = threadIdx.x & 63;
  if (wave >= NN) return;
  int n = wave;
  int cbase = lane * 8;
  float dn = dinv[n];
  floatx8 acc;
  {
    float wself = dn * dn;
    ushortx8 hv = *(const ushortx8*)(hw + (size_t)n * DD + cbase);
    #pragma unroll
    for (int j = 0; j < 8; ++j) acc[j] = wself * bf2f(hv[j]);
  }
  int beg = offs[n], end = offs[n + 1];
  int scur = srcs[beg];                    // padded
  for (int p = beg; p < end; ++p) {
    int s = scur;
    scur = srcs[p + 1];
    float wgt = dinv_src[p] * dn;
    ushortx8 hv = *(const ushortx8*)(hw + (size_t)s * DD + cbase);
    #pragma unroll
    for (int j = 0; j < 8; ++j) acc[j] = fmaf(wgt, bf2f(hv[j]), acc[j]);
  }
  ushortx8 rv = *(const ushortx8*)(Xbf + (size_t)n * DD + cbase);
  floatx8 v;
  float s = 0.f, sq = 0.f;
  #pragma unroll
  for (int j = 0; j < 8; ++j) {
    float g = acc[j] + bias[cbase + j];
    float t = fmaxf(g, 0.f) + bf2f(rv[j]);
    v[j] = t;
    s += t; sq += t * t;
  }
  s = wave_sum_u(s);
  sq = wave_sum_u(sq);
  float mu = s * (1.f / DD);
  float var = sq * (1.f / DD) - mu * mu;
  float rstd = rsqrtf(var + 1e-5f);
  if (outf) {
    float4* o4 = (float4*)(outf + (size_t)n * DD + cbase);
    float4 oa, ob4;
    oa.x = fmaf((v[0] - mu) * rstd, gamma[cbase + 0], beta[cbase + 0]);
    oa.y = fmaf((v[1] - mu) * rstd, gamma[cbase + 1], beta[cbase + 1]);
    oa.z = fmaf((v[2] - mu) * rstd, gamma[cbase + 2], beta[cbase + 2]);
    oa.w = fmaf((v[3] - mu) * rstd, gamma[cbase + 3], beta[cbase + 3]);
    ob4.x = fmaf((v[4] - mu) * rstd, gamma[cbase + 4], beta[cbase + 4]);
    ob4.y = fmaf((v[5] - mu) * rstd, gamma[cbase + 5], beta[cbase + 5]);
    ob4.z = fmaf((v[6] - mu) * rstd, gamma[cbase + 6], beta[cbase + 6]);
    ob4.w = fmaf((v[7] - mu) * rstd, gamma[cbase + 7], beta[cbase + 7]);
    o4[0] = oa;
    o4[1] = ob4;
  } else {
    ushortx8 ob;
    #pragma unroll
    for (int j = 0; j < 8; ++j)
      ob[j] = f2bf(fmaf((v[j] - mu) * rstd, gamma[cbase + j], beta[cbase + j]));
    *(ushortx8*)(Xbf + (size_t)n * DD + cbase) = ob;
  }
}

// ---------------- host-side launcher ----------------
static void launch_bgemm(const unsigned short* A, const unsigned short* Bt,
                         const float* bias, unsigned short* C, int M, int Nc, int K,
                         int act, hipStream_t stream) {
  dim3 grid(Nc / 128, M / 128);
  k_bgemm<<<grid, 256, 0, stream>>>(A, Bt, bias, C, M, Nc, K, act);
}

extern "C" void kernel_launch(void* const* d_in, const int* in_sizes, int n_in,
                              void* d_out, int out_size, void* d_ws, size_t ws_size,
                              hipStream_t stream) {
  const float* x       = (const float*)d_in[0];
  const int*   eidx    = (const int*)d_in[1];
  const float* eattr   = (const float*)d_in[2];
  const float* Wproj   = (const float*)d_in[3];
  const float* bproj   = (const float*)d_in[4];
  const float* geW     = (const float*)d_in[5];
  const float* geb     = (const float*)d_in[6];
  const float* gW1     = (const float*)d_in[7];
  const float* gb1     = (const float*)d_in[8];
  const float* gW2     = (const float*)d_in[9];
  const float* gb2     = (const float*)d_in[10];
  const float* gatWl   = (const float*)d_in[11];
  const float* gatbl   = (const float*)d_in[12];
  const float* gatWr   = (const float*)d_in[13];
  const float* gatbr   = (const float*)d_in[14];
  const float* gateW   = (const float*)d_in[15];
  const float* gatatt  = (const float*)d_in[16];
  const float* gatbias = (const float*)d_in[17];
  const float* gcn1W   = (const float*)d_in[18];
  const float* gcn1b   = (const float*)d_in[19];
  const float* gcn2W   = (const float*)d_in[20];
  const float* gcn2b   = (const float*)d_in[21];
  const float* lgamma  = (const float*)d_in[22];
  const float* lbeta   = (const float*)d_in[23];
  const int* srcArr = eidx;
  const int* dstArr = eidx + EE;

  // ---- workspace carving (~105 MB) ----
  char* p = (char*)d_ws;
  unsigned short* Hacc = (unsigned short*)p; p += (size_t)NN * DD * 2;       // 16MB bf16 accum
  unsigned short* Xbf = (unsigned short*)p; p += (size_t)NN * DD * 2;        // 16MB
  unsigned short* U   = (unsigned short*)p; p += (size_t)NN * 2048 * 2;      // 64MB union
  unsigned short* w1t = (unsigned short*)p; p += (size_t)1024 * 512 * 2;
  unsigned short* w2t = (unsigned short*)p; p += (size_t)512 * 1024 * 2;
  unsigned short* wc0 = (unsigned short*)p; p += (size_t)2048 * 512 * 2;
  unsigned short* wc1 = (unsigned short*)p; p += (size_t)2048 * 512 * 2;
  unsigned short* g1t = (unsigned short*)p; p += (size_t)512 * 512 * 2;
  unsigned short* g2t = (unsigned short*)p; p += (size_t)512 * 512 * 2;
  float4* ea4     = (float4*)p;         p += (size_t)(EE + 4) * 16;      // 1MB (16B aligned)
  float* bc0      = (float*)p;          p += 2048 * 4;
  float* bc1      = (float*)p;          p += 2048 * 4;
  float* macc     = (float*)p;          p += 4 * 4;
  float* dinv     = (float*)p;          p += (size_t)NN * 4;
  float* dinv_src = (float*)p;          p += (size_t)(EE + 16) * 4;
  int*   cnt      = (int*)p;            p += (size_t)NN * 4;
  int*   offs     = (int*)p;            p += (size_t)(NN + 1) * 4 + 12;
  int*   cursor   = (int*)p;            p += (size_t)NN * 4;
  int*   srcs     = (int*)p;            p += (size_t)(EE + 16) * 4;

  unsigned short* Zbf = U;                       // NN x 512 (GINE agg out)
  unsigned short* Ybf = U + (size_t)NN * 512;    // NN x 1024 (MLP mid)
  unsigned short* Gbf = U + (size_t)NN * 1536;   // NN x 512 (MLP out, bf16)
  unsigned short* XLR = U;                       // NN x 2048 (GAT xl|xr, 2 heads)
  unsigned short* hw  = U;                       // NN x 512 (GCN h@W)

  hipMemsetAsync(cnt, 0, NN * sizeof(int), stream);
  hipMemsetAsync(cursor, 0, NN * sizeof(int), stream);
  hipMemsetAsync(macc, 0, 4 * sizeof(float), stream);

  k_edge_prep<<<128, 256, 0, stream>>>(dstArr, eattr, cnt, macc);
  k_scan<<<1, 256, 0, stream>>>(cnt, offs, dinv);
  k_fill<<<EE / 256, 256, 0, stream>>>(dstArr, srcArr, eattr, offs, dinv,
                                       cursor, srcs, ea4, dinv_src);

  // weight prep
  {
    k_transcast<<<dim3(1024 / 32, 512 / 32), 256, 0, stream>>>(gW1, 1024, w1t, 512, 1024);
    k_transcast<<<dim3(512 / 32, 1024 / 32), 256, 0, stream>>>(gW2, 512, w2t, 1024, 512);
    k_transcast<<<dim3(1024 / 32, 512 / 32), 256, 0, stream>>>(gatWl, 2048, wc0, 512, 1024);
    k_transcast<<<dim3(1024 / 32, 512 / 32), 256, 0, stream>>>(gatWr, 2048, wc0 + (size_t)1024 * 512, 512, 1024);
    k_transcast<<<dim3(1024 / 32, 512 / 32), 256, 0, stream>>>(gatWl + 1024, 2048, wc1, 512, 1024);
    k_transcast<<<dim3(1024 / 32, 512 / 32), 256, 0, stream>>>(gatWr + 1024, 2048, wc1 + (size_t)1024 * 512, 512, 1024);
    k_transcast<<<dim3(512 / 32, 512 / 32), 256, 0, stream>>>(gcn1W, 512, g1t, 512, 512);
    k_transcast<<<dim3(512 / 32, 512 / 32), 256, 0, stream>>>(gcn2W, 512, g2t, 512, 512);
    k_bcomb<<<16, 256, 0, stream>>>(gatbl, gatbr, bc0, bc1);
  }

  // input projection (bf16 only)
  k_proj<<<NN * DD / 256, 256, 0, stream>>>(x, Wproj, bproj, Xbf);

  // ---- layer 0: GINEConv + MLP + LN (MLP out bf16) ----
  k_gine_agg<<<NN / 4, 256, 0, stream>>>(Xbf, srcs, ea4, geW, geb, offs, Zbf);
  launch_bgemm(Zbf, w1t, gb1, Ybf, NN, 1024, 512, 1, stream);
  launch_bgemm(Ybf, w2t, gb2, Gbf, NN, 512, 1024, 0, stream);
  k_ln0<<<NN / 4, 256, 0, stream>>>(Gbf, Xbf, lgamma, lbeta, Xbf);

  // ---- layer 1: GATv2, two 2-head batches; per-(node,head) waves ----
  for (int b = 0; b < 2; ++b) {
    launch_bgemm(Xbf, b ? wc1 : wc0, b ? bc1 : bc0, XLR, NN, 2048, 512, 0, stream);
    k_gat_fused<<<NN / 2, 256, 0, stream>>>(XLR, srcs, offs, ea4, macc,
                                            gateW, gatatt, Hacc, Xbf, gatbias,
                                            lgamma + DD, lbeta + DD, b);
  }

  // ---- layers 2,3: GCN (aggregate + fused LN) ----
  launch_bgemm(Xbf, g1t, nullptr, hw, NN, 512, 512, 0, stream);
  k_gcn_ln<<<NN / 4, 256, 0, stream>>>(hw, srcs, offs, dinv_src, dinv, gcn1b,
                                       lgamma + 2 * DD, lbeta + 2 * DD, Xbf, nullptr);
  launch_bgemm(Xbf, g2t, nullptr, hw, NN, 512, 512, 0, stream);
  k_gcn_ln<<<NN / 4, 256, 0, stream>>>(hw, srcs, offs, dinv_src, dinv, gcn2b,
                                       lgamma + 3 * DD, lbeta + 3 * DD, Xbf, (float*)d_out);
}

// Round 9
// 526.598 us; speedup vs baseline: 1.1280x; 1.0663x over previous
//
#include <hip/hip_runtime.h>
#include <hip/hip_bf16.h>
#include <math.h>

#define NN   16384
#define EE   65536
#define DD   512
#define HH   4
#define FINN 7

typedef __attribute__((ext_vector_type(4))) float  floatx4;
typedef __attribute__((ext_vector_type(8))) float  floatx8;
typedef __attribute__((ext_vector_type(8))) short  shortx8;
typedef __attribute__((ext_vector_type(8))) unsigned short ushortx8;

// ---------------- helpers ----------------
__device__ inline float bf2f(unsigned short u) {
  return __uint_as_float(((unsigned)u) << 16);
}
__device__ inline unsigned short f2bf(float f) {
  unsigned u = __float_as_uint(f);
  unsigned r = (u + 0x7fffu + ((u >> 16) & 1u)) >> 16;
  return (unsigned short)r;
}
__device__ inline float wave_reduce_sum(float v) {
  #pragma unroll
  for (int off = 32; off > 0; off >>= 1) v += __shfl_down(v, off, 64);
  return v;
}
// wave64 sum via DPP: row_shr 1/2/4/8 (lane 15 of each 16-row = row sum),
// row_bcast15 (lane31=r0+r1, lane63=r2+r3), row_bcast31 (lane63=total).
// readlane(63) -> wave-uniform. All-lanes-active contexts only.
__device__ inline float wave_sum_u(float v) {
  v += __int_as_float(__builtin_amdgcn_update_dpp(0, __float_as_int(v), 0x111, 0xf, 0xf, true));
  v += __int_as_float(__builtin_amdgcn_update_dpp(0, __float_as_int(v), 0x112, 0xf, 0xf, true));
  v += __int_as_float(__builtin_amdgcn_update_dpp(0, __float_as_int(v), 0x114, 0xf, 0xf, true));
  v += __int_as_float(__builtin_amdgcn_update_dpp(0, __float_as_int(v), 0x118, 0xf, 0xf, true));
  v += __int_as_float(__builtin_amdgcn_update_dpp(0, __float_as_int(v), 0x142, 0xf, 0xf, true));
  v += __int_as_float(__builtin_amdgcn_update_dpp(0, __float_as_int(v), 0x143, 0xf, 0xf, true));
  return __int_as_float(__builtin_amdgcn_readlane(__float_as_int(v), 63));
}
__device__ inline void async16(const unsigned short* g, unsigned short* l) {
  __builtin_amdgcn_global_load_lds(
      (const __attribute__((address_space(1))) void*)g,
      (__attribute__((address_space(3))) void*)l, 16, 0, 0);
}

// ---------------- CSR build ----------------
// fused degree-count + edge_attr mean (one pass over edges)
__global__ void k_edge_prep(const int* __restrict__ dst, const float* __restrict__ eattr,
                            int* __restrict__ cnt, float* __restrict__ macc) {
  int tid = blockIdx.x * blockDim.x + threadIdx.x;
  int stride = gridDim.x * blockDim.x;
  float ax = 0.f, ay = 0.f, az = 0.f, aw = 0.f;
  for (int e = tid; e < EE; e += stride) {
    atomicAdd(&cnt[dst[e]], 1);
    float4 v = ((const float4*)eattr)[e];
    ax += v.x; ay += v.y; az += v.z; aw += v.w;
  }
  ax = wave_reduce_sum(ax); ay = wave_reduce_sum(ay);
  az = wave_reduce_sum(az); aw = wave_reduce_sum(aw);
  if ((threadIdx.x & 63) == 0) {
    atomicAdd(&macc[0], ax); atomicAdd(&macc[1], ay);
    atomicAdd(&macc[2], az); atomicAdd(&macc[3], aw);
  }
}

// k_scan also emits dinv
__global__ void k_scan(const int* __restrict__ cnt, int* __restrict__ offs,
                       float* __restrict__ dinv) {
  __shared__ int sums[256];
  int t = threadIdx.x;
  const int chunk = NN / 256;
  int base = t * chunk;
  int s = 0;
  for (int i = 0; i < chunk; ++i) {
    int c = cnt[base + i];
    s += c;
    dinv[base + i] = rsqrtf((float)c + 1.0f);
  }
  sums[t] = s;
  __syncthreads();
  for (int off = 1; off < 256; off <<= 1) {
    int v = (t >= off) ? sums[t - off] : 0;
    __syncthreads();
    sums[t] += v;
    __syncthreads();
  }
  int run = (t == 0) ? 0 : sums[t - 1];
  for (int i = 0; i < chunk; ++i) {
    offs[base + i] = run;
    run += cnt[base + i];
  }
  if (t == 255) offs[NN] = run;
}

// k_fill materializes CSR-ordered src ids, edge attrs, and dinv[src]
__global__ void k_fill(const int* __restrict__ dst, const int* __restrict__ src,
                       const float* __restrict__ eattr, const int* __restrict__ offs,
                       const float* __restrict__ dinv,
                       int* __restrict__ cursor, int* __restrict__ srcs,
                       float4* __restrict__ ea4, float* __restrict__ dinv_src) {
  int e = blockIdx.x * 256 + threadIdx.x;
  if (e >= EE) return;
  int d = dst[e];
  int p = offs[d] + atomicAdd(&cursor[d], 1);
  int s = src[e];
  srcs[p] = s;
  ea4[p] = ((const float4*)eattr)[e];
  dinv_src[p] = dinv[s];
}

// ------------- weight transpose+cast: W slice (K x N, ld) f32 -> Wt[N][K] bf16 -------
__global__ void k_transcast(const float* __restrict__ W, int ld,
                            unsigned short* __restrict__ Wt, int K, int N) {
  __shared__ float tile[32][33];
  int bx = blockIdx.x;
  int by = blockIdx.y;
  int tx = threadIdx.x & 31, ty = threadIdx.x >> 5;
  #pragma unroll
  for (int i = 0; i < 32; i += 8)
    tile[ty + i][tx] = W[(size_t)(by * 32 + ty + i) * ld + bx * 32 + tx];
  __syncthreads();
  #pragma unroll
  for (int i = 0; i < 32; i += 8)
    Wt[(size_t)(bx * 32 + ty + i) * K + by * 32 + tx] = f2bf(tile[tx][ty + i]);
}

// ------------- combined GAT bias ----------------
__global__ void k_bcomb(const float* __restrict__ bl, const float* __restrict__ br,
                        float* __restrict__ bc0, float* __restrict__ bc1) {
  int i = blockIdx.x * 256 + threadIdx.x;
  if (i >= 4096) return;
  int b = i >> 11, c = i & 2047;
  float v = (c < 1024) ? bl[b * 1024 + c] : br[b * 1024 + c - 1024];
  (b ? bc1 : bc0)[c] = v;
}

// ---------------- input projection ----------------
__global__ void k_proj(const float* __restrict__ x, const float* __restrict__ W,
                       const float* __restrict__ b, unsigned short* __restrict__ hbf) {
  int gid = blockIdx.x * 256 + threadIdx.x;
  if (gid >= NN * DD) return;
  int n = gid >> 9, d = gid & 511;
  const float* xr = x + n * FINN;
  float acc = b[d];
  #pragma unroll
  for (int k = 0; k < FINN; ++k) acc = fmaf(xr[k], W[k * DD + d], acc);
  hbf[gid] = f2bf(fmaxf(acc, 0.f));
}

// ---------------- bf16 MFMA GEMM, XOR-swizzled LDS, XCD swizzle --------------------
// r15: K is a compile-time template param. At K=512 only 8 K-iters amortize
// addressing; runtime-K forced per-iter 64-bit addr recompute (8x mad_u64
// class sequences/iter ~= the MFMA cost itself; VALUBusy 39% vs MfmaUtil 21%).
// Now: per-thread stream pointers hoisted, advanced += 64/iter; K/64 trip
// count is static and fully unrolled -> all LDS offsets/addressing static.
// LDS-staged coalesced epilogue (r14) unchanged.
template <int K>
__global__ __launch_bounds__(256) void k_bgemm(
    const unsigned short* __restrict__ A, const unsigned short* __restrict__ Bt,
    const float* __restrict__ bias, unsigned short* __restrict__ Cout,
    int Nc, int act) {
  __shared__ unsigned short S[16384];   // 32KB: A(8192) | B(8192), then C tile
  unsigned short* As = S;
  unsigned short* Bs = S + 8192;
  const int tid = threadIdx.x;
  const int wv = tid >> 6;
  const int lane = tid & 63;
  // bijective XCD swizzle (nwg % 8 == 0 for all our launches)
  int gx = gridDim.x;
  int nwg = gx * gridDim.y;
  int wg = blockIdx.y * gx + blockIdx.x;
  if ((nwg & 7) == 0) {
    int cpx = nwg >> 3;
    wg = (wg & 7) * cpx + (wg >> 3);
  }
  const int row0 = (wg / gx) * 128;
  const int col0 = (wg % gx) * 128;
  const int wrow = (wv & 1) * 64;
  const int wcol = (wv >> 1) * 64;

  floatx4 acc[4][4];
  #pragma unroll
  for (int r = 0; r < 4; ++r)
    #pragma unroll
    for (int c = 0; c < 4; ++c)
      #pragma unroll
      for (int q = 0; q < 4; ++q) acc[r][c][q] = 0.f;

  const int lrow = lane >> 3;                       // 0..7 within segment
  const int lchunk = (lane & 7) ^ lrow;             // swizzled source k-chunk
  const int lk = lchunk * 8;                        // shorts

  // hoisted per-thread stream pointers (static after full unroll)
  const unsigned short* ap[4];
  const unsigned short* bp[4];
  #pragma unroll
  for (int i = 0; i < 4; ++i) {
    int seg = i * 4 + wv;
    int r = seg * 8 + lrow;
    ap[i] = A + (size_t)(row0 + r) * K + lk;
    bp[i] = Bt + (size_t)(col0 + r) * K + lk;
  }

  const int frow = lane & 15;
  const int fx = lane >> 4;
  const int fsw = lane & 7;

  #pragma unroll
  for (int kk = 0; kk < K / 64; ++kk) {
    #pragma unroll
    for (int i = 0; i < 4; ++i) {
      int seg = i * 4 + wv;
      async16(ap[i], &As[seg * 512]);
      async16(bp[i], &Bs[seg * 512]);
      ap[i] += 64;
      bp[i] += 64;
    }
    __syncthreads();
    #pragma unroll
    for (int s = 0; s < 2; ++s) {
      int ch = ((s * 4 + fx) ^ fsw) * 8;
      shortx8 af[4], bfr[4];
      #pragma unroll
      for (int r = 0; r < 4; ++r)
        af[r] = *(const shortx8*)&As[(wrow + r * 16 + frow) * 64 + ch];
      #pragma unroll
      for (int c = 0; c < 4; ++c)
        bfr[c] = *(const shortx8*)&Bs[(wcol + c * 16 + frow) * 64 + ch];
      #pragma unroll
      for (int r = 0; r < 4; ++r)
        #pragma unroll
        for (int c = 0; c < 4; ++c)
          acc[r][c] = __builtin_amdgcn_mfma_f32_16x16x32_bf16(af[r], bfr[c], acc[r][c], 0, 0, 0);
    }
    __syncthreads();
  }

  // ---- epilogue: bias/act, stage bf16 C tile in LDS, coalesced store ----
  #pragma unroll
  for (int r = 0; r < 4; ++r) {
    int lr0 = wrow + r * 16 + (lane >> 4) * 4;       // local row base
    #pragma unroll
    for (int c = 0; c < 4; ++c) {
      int lc = wcol + c * 16 + (lane & 15);          // local col
      float bv = bias ? bias[col0 + lc] : 0.f;
      #pragma unroll
      for (int q = 0; q < 4; ++q) {
        float v = acc[r][c][q] + bv;
        if (act) v = fmaxf(v, 0.f);
        S[(lr0 + q) * 128 + lc] = f2bf(v);
      }
    }
  }
  __syncthreads();
  #pragma unroll
  for (int i = 0; i < 8; ++i) {
    int idx = (i * 256 + tid) * 8;                   // short index in tile
    int lr = idx >> 7;
    int lc = idx & 127;
    *(ushortx8*)(Cout + (size_t)(row0 + lr) * Nc + col0 + lc) =
        *(const ushortx8*)&S[idx];
  }
}

// ------------- GINE aggregate (CSR-ordered srcs/ea4, no indirection) --------
__global__ void k_gine_agg(const unsigned short* __restrict__ hbf,
                           const int* __restrict__ srcs, const float4* __restrict__ ea4,
                           const float* __restrict__ geW, const float* __restrict__ geb,
                           const int* __restrict__ offs,
                           unsigned short* __restrict__ gbf) {
  int wave = (blockIdx.x * blockDim.x + threadIdx.x) >> 6;
  int lane = threadIdx.x & 63;
  if (wave >= NN) return;
  int n = wave;
  int cbase = lane * 8;
  floatx8 w0, w1, w2, w3, bb;
  #pragma unroll
  for (int j = 0; j < 8; ++j) {
    bb[j] = geb[cbase + j];
    w0[j] = geW[0 * DD + cbase + j];
    w1[j] = geW[1 * DD + cbase + j];
    w2[j] = geW[2 * DD + cbase + j];
    w3[j] = geW[3 * DD + cbase + j];
  }
  floatx8 acc = {0.f, 0.f, 0.f, 0.f, 0.f, 0.f, 0.f, 0.f};
  int beg = offs[n], end = offs[n + 1];
  int scur = srcs[beg];                    // padded array: srcs[EE] readable
  for (int p = beg; p < end; ++p) {
    int s = scur;
    scur = srcs[p + 1];                    // branchless one-ahead (padded)
    float4 ea = ea4[p];
    ushortx8 hv = *(const ushortx8*)(hbf + (size_t)s * DD + cbase);
    #pragma unroll
    for (int j = 0; j < 8; ++j) {
      float ev = bb[j];
      ev = fmaf(ea.x, w0[j], ev);
      ev = fmaf(ea.y, w1[j], ev);
      ev = fmaf(ea.z, w2[j], ev);
      ev = fmaf(ea.w, w3[j], ev);
      acc[j] += fmaxf(bf2f(hv[j]) + ev, 0.f);
    }
  }
  ushortx8 hn = *(const ushortx8*)(hbf + (size_t)n * DD + cbase);
  ushortx8 o;
  #pragma unroll
  for (int j = 0; j < 8; ++j) o[j] = f2bf(bf2f(hn[j]) + acc[j]);
  *(ushortx8*)(gbf + (size_t)n * DD + cbase) = o;
}

// -------- layer-0 LayerNorm ----------------
__global__ void k_ln0(const unsigned short* __restrict__ g, const unsigned short* __restrict__ res,
                      const float* __restrict__ gamma, const float* __restrict__ beta,
                      unsigned short* __restrict__ obf) {
  int wave = (blockIdx.x * blockDim.x + threadIdx.x) >> 6;
  int lane = threadIdx.x & 63;
  if (wave >= NN) return;
  int n = wave;
  int cbase = lane * 8;
  ushortx8 gv = *(const ushortx8*)(g + (size_t)n * DD + cbase);
  ushortx8 rv = *(const ushortx8*)(res + (size_t)n * DD + cbase);
  floatx8 v;
  float s = 0.f, sq = 0.f;
  #pragma unroll
  for (int j = 0; j < 8; ++j) {
    float t = fmaxf(bf2f(gv[j]), 0.f) + bf2f(rv[j]);
    v[j] = t;
    s += t; sq += t * t;
  }
  s = wave_sum_u(s);
  sq = wave_sum_u(sq);
  float mu = s * (1.f / DD);
  float var = sq * (1.f / DD) - mu * mu;
  float rstd = rsqrtf(var + 1e-5f);
  ushortx8 ob;
  #pragma unroll
  for (int j = 0; j < 8; ++j)
    ob[j] = f2bf(fmaf((v[j] - mu) * rstd, gamma[cbase + j], beta[cbase + j]));
  *(ushortx8*)(obf + (size_t)n * DD + cbase) = ob;
}

// ======== fused GATv2: per-(node,head) waves, DPP logit reduce ========
// Block = 256 threads = 4 waves = 2 nodes x 2 heads. Grid = NN/2.
__global__ __launch_bounds__(256) void k_gat_fused(
    const unsigned short* __restrict__ xlr,
    const int* __restrict__ srcs,
    const int* __restrict__ offs, const float4* __restrict__ ea4,
    const float* __restrict__ macc,
    const float* __restrict__ geW /*4x2048*/,
    const float* __restrict__ att /*4x512 (HxC)*/,
    unsigned short* __restrict__ Hacc, unsigned short* __restrict__ Xbf,
    const float* __restrict__ gbias,
    const float* __restrict__ gamma, const float* __restrict__ beta,
    int batch) {
  __shared__ float lsum[2][512];          // head-1 normalized sums, per node-slot
  int wv = threadIdx.x >> 6;              // 0..3
  int lane = threadIdx.x & 63;
  int slot = wv >> 1;                     // node slot in block (0,1)
  int h = wv & 1;                         // head within batch
  int n = blockIdx.x * 2 + slot;
  int c8 = lane * 8;
  int hoff = h * 512;                     // xl/xr slice offset (shorts)
  int hc = (2 * batch + h) * 512 + c8;    // channel base in 2048-wide weights
  const float invE = 1.f / EE;
  float meax = macc[0] * invE, meay = macc[1] * invE;
  float meaz = macc[2] * invE, meaw = macc[3] * invE;
  int beg = offs[n], end = offs[n + 1];

  floatx8 w0, w1, w2, w3, at, xr;
  #pragma unroll
  for (int j = 0; j < 8; ++j) {
    w0[j] = geW[0 * (HH * DD) + hc + j];
    w1[j] = geW[1 * (HH * DD) + hc + j];
    w2[j] = geW[2 * (HH * DD) + hc + j];
    w3[j] = geW[3 * (HH * DD) + hc + j];
    at[j] = att[hc + j];
  }
  {
    ushortx8 rr = *(const ushortx8*)(xlr + (size_t)n * 2048 + 1024 + hoff + c8);
    #pragma unroll
    for (int j = 0; j < 8; ++j) xr[j] = bf2f(rr[j]);
  }

  float l;
  floatx8 acc;
  // ---- self-loop (edge attr = mean) ----
  {
    ushortx8 a = *(const ushortx8*)(xlr + (size_t)n * 2048 + hoff + c8);
    float z = 0.f;
    #pragma unroll
    for (int j = 0; j < 8; ++j) {
      float t = bf2f(a[j]) + xr[j];
      t = fmaf(meax, w0[j], t);
      t = fmaf(meay, w1[j], t);
      t = fmaf(meaz, w2[j], t);
      t = fmaf(meaw, w3[j], t);
      t = (t >= 0.f) ? t : 0.2f * t;
      z = fmaf(t, at[j], z);
    }
    float w = __expf(wave_sum_u(z));
    l = w;
    #pragma unroll
    for (int j = 0; j < 8; ++j) acc[j] = w * bf2f(a[j]);
  }
  // ---- CSR edges (this head only; branchless one-ahead src) ----
  int scur = srcs[beg];                    // padded: srcs[EE] readable
  for (int p = beg; p < end; ++p) {
    int s = scur;
    scur = srcs[p + 1];
    float4 ea = ea4[p];
    ushortx8 a = *(const ushortx8*)(xlr + (size_t)s * 2048 + hoff + c8);
    float z = 0.f;
    #pragma unroll
    for (int j = 0; j < 8; ++j) {
      float t = bf2f(a[j]) + xr[j];
      t = fmaf(ea.x, w0[j], t);
      t = fmaf(ea.y, w1[j], t);
      t = fmaf(ea.z, w2[j], t);
      t = fmaf(ea.w, w3[j], t);
      t = (t >= 0.f) ? t : 0.2f * t;
      z = fmaf(t, at[j], z);
    }
    float w = __expf(wave_sum_u(z));
    l += w;
    #pragma unroll
    for (int j = 0; j < 8; ++j) acc[j] = fmaf(w, bf2f(a[j]), acc[j]);
  }

  float inv = 1.f / (l + 1e-16f);
  // head-1 waves publish their normalized sums; head-0 waves combine.
  if (h) {
    #pragma unroll
    for (int j = 0; j < 8; ++j) lsum[slot][c8 + j] = acc[j] * inv;
  }
  __syncthreads();
  if (h) return;

  floatx8 hsum;
  #pragma unroll
  for (int j = 0; j < 8; ++j) hsum[j] = acc[j] * inv + lsum[slot][c8 + j];

  unsigned short* hp = Hacc + (size_t)n * DD + c8;
  if (batch == 0) {
    ushortx8 o;
    #pragma unroll
    for (int j = 0; j < 8; ++j) o[j] = f2bf(hsum[j]);
    *(ushortx8*)hp = o;
    return;
  }
  // batch 1: mean over 4 heads, +bias, relu, +residual, LN, write bf16
  ushortx8 pv = *(const ushortx8*)hp;
  ushortx8 rv = *(const ushortx8*)(Xbf + (size_t)n * DD + c8);
  floatx8 v;
  float s = 0.f, sq = 0.f;
  #pragma unroll
  for (int j = 0; j < 8; ++j) {
    float g = (bf2f(pv[j]) + hsum[j]) * 0.25f + gbias[c8 + j];
    float val = fmaxf(g, 0.f) + bf2f(rv[j]);
    v[j] = val;
    s += val; sq += val * val;
  }
  s = wave_sum_u(s);
  sq = wave_sum_u(sq);
  float mu = s * (1.f / DD);
  float var = sq * (1.f / DD) - mu * mu;
  float rstd = rsqrtf(var + 1e-5f);
  ushortx8 ob;
  #pragma unroll
  for (int j = 0; j < 8; ++j)
    ob[j] = f2bf(fmaf((v[j] - mu) * rstd, gamma[c8 + j], beta[c8 + j]));
  *(ushortx8*)(Xbf + (size_t)n * DD + c8) = ob;
}

// ---------------- GCN aggregate + fused bias/relu/res/LN ----------------
__global__ void k_gcn_ln(const unsigned short* __restrict__ hw, const int* __restrict__ srcs,
                         const int* __restrict__ offs, const float* __restrict__ dinv_src,
                         const float* __restrict__ dinv, const float* __restrict__ bias,
                         const float* __restrict__ gamma, const float* __restrict__ beta,
                         unsigned short* __restrict__ Xbf, float* __restrict__ outf) {
  int wave = (blockIdx.x * blockDim.x + threadIdx.x) >> 6;
  int lane = threadIdx.x & 63;
  if (wave >= NN) return;
  int n = wave;
  int cbase = lane * 8;
  float dn = dinv[n];
  floatx8 acc;
  {
    float wself = dn * dn;
    ushortx8 hv = *(const ushortx8*)(hw + (size_t)n * DD + cbase);
    #pragma unroll
    for (int j = 0; j < 8; ++j) acc[j] = wself * bf2f(hv[j]);
  }
  int beg = offs[n], end = offs[n + 1];
  int scur = srcs[beg];                    // padded
  for (int p = beg; p < end; ++p) {
    int s = scur;
    scur = srcs[p + 1];
    float wgt = dinv_src[p] * dn;
    ushortx8 hv = *(const ushortx8*)(hw + (size_t)s * DD + cbase);
    #pragma unroll
    for (int j = 0; j < 8; ++j) acc[j] = fmaf(wgt, bf2f(hv[j]), acc[j]);
  }
  ushortx8 rv = *(const ushortx8*)(Xbf + (size_t)n * DD + cbase);
  floatx8 v;
  float s = 0.f, sq = 0.f;
  #pragma unroll
  for (int j = 0; j < 8; ++j) {
    float g = acc[j] + bias[cbase + j];
    float t = fmaxf(g, 0.f) + bf2f(rv[j]);
    v[j] = t;
    s += t; sq += t * t;
  }
  s = wave_sum_u(s);
  sq = wave_sum_u(sq);
  float mu = s * (1.f / DD);
  float var = sq * (1.f / DD) - mu * mu;
  float rstd = rsqrtf(var + 1e-5f);
  if (outf) {
    float4* o4 = (float4*)(outf + (size_t)n * DD + cbase);
    float4 oa, ob4;
    oa.x = fmaf((v[0] - mu) * rstd, gamma[cbase + 0], beta[cbase + 0]);
    oa.y = fmaf((v[1] - mu) * rstd, gamma[cbase + 1], beta[cbase + 1]);
    oa.z = fmaf((v[2] - mu) * rstd, gamma[cbase + 2], beta[cbase + 2]);
    oa.w = fmaf((v[3] - mu) * rstd, gamma[cbase + 3], beta[cbase + 3]);
    ob4.x = fmaf((v[4] - mu) * rstd, gamma[cbase + 4], beta[cbase + 4]);
    ob4.y = fmaf((v[5] - mu) * rstd, gamma[cbase + 5], beta[cbase + 5]);
    ob4.z = fmaf((v[6] - mu) * rstd, gamma[cbase + 6], beta[cbase + 6]);
    ob4.w = fmaf((v[7] - mu) * rstd, gamma[cbase + 7], beta[cbase + 7]);
    o4[0] = oa;
    o4[1] = ob4;
  } else {
    ushortx8 ob;
    #pragma unroll
    for (int j = 0; j < 8; ++j)
      ob[j] = f2bf(fmaf((v[j] - mu) * rstd, gamma[cbase + j], beta[cbase + j]));
    *(ushortx8*)(Xbf + (size_t)n * DD + cbase) = ob;
  }
}

// ---------------- host-side launcher ----------------
static void launch_bgemm(const unsigned short* A, const unsigned short* Bt,
                         const float* bias, unsigned short* C, int M, int Nc, int K,
                         int act, hipStream_t stream) {
  dim3 grid(Nc / 128, M / 128);
  if (K == 512)
    k_bgemm<512><<<grid, 256, 0, stream>>>(A, Bt, bias, C, Nc, act);
  else
    k_bgemm<1024><<<grid, 256, 0, stream>>>(A, Bt, bias, C, Nc, act);
}

extern "C" void kernel_launch(void* const* d_in, const int* in_sizes, int n_in,
                              void* d_out, int out_size, void* d_ws, size_t ws_size,
                              hipStream_t stream) {
  const float* x       = (const float*)d_in[0];
  const int*   eidx    = (const int*)d_in[1];
  const float* eattr   = (const float*)d_in[2];
  const float* Wproj   = (const float*)d_in[3];
  const float* bproj   = (const float*)d_in[4];
  const float* geW     = (const float*)d_in[5];
  const float* geb     = (const float*)d_in[6];
  const float* gW1     = (const float*)d_in[7];
  const float* gb1     = (const float*)d_in[8];
  const float* gW2     = (const float*)d_in[9];
  const float* gb2     = (const float*)d_in[10];
  const float* gatWl   = (const float*)d_in[11];
  const float* gatbl   = (const float*)d_in[12];
  const float* gatWr   = (const float*)d_in[13];
  const float* gatbr   = (const float*)d_in[14];
  const float* gateW   = (const float*)d_in[15];
  const float* gatatt  = (const float*)d_in[16];
  const float* gatbias = (const float*)d_in[17];
  const float* gcn1W   = (const float*)d_in[18];
  const float* gcn1b   = (const float*)d_in[19];
  const float* gcn2W   = (const float*)d_in[20];
  const float* gcn2b   = (const float*)d_in[21];
  const float* lgamma  = (const float*)d_in[22];
  const float* lbeta   = (const float*)d_in[23];
  const int* srcArr = eidx;
  const int* dstArr = eidx + EE;

  // ---- workspace carving (~105 MB) ----
  char* p = (char*)d_ws;
  unsigned short* Hacc = (unsigned short*)p; p += (size_t)NN * DD * 2;       // 16MB bf16 accum
  unsigned short* Xbf = (unsigned short*)p; p += (size_t)NN * DD * 2;        // 16MB
  unsigned short* U   = (unsigned short*)p; p += (size_t)NN * 2048 * 2;      // 64MB union
  unsigned short* w1t = (unsigned short*)p; p += (size_t)1024 * 512 * 2;
  unsigned short* w2t = (unsigned short*)p; p += (size_t)512 * 1024 * 2;
  unsigned short* wc0 = (unsigned short*)p; p += (size_t)2048 * 512 * 2;
  unsigned short* wc1 = (unsigned short*)p; p += (size_t)2048 * 512 * 2;
  unsigned short* g1t = (unsigned short*)p; p += (size_t)512 * 512 * 2;
  unsigned short* g2t = (unsigned short*)p; p += (size_t)512 * 512 * 2;
  float4* ea4     = (float4*)p;         p += (size_t)(EE + 4) * 16;      // 1MB (16B aligned)
  float* bc0      = (float*)p;          p += 2048 * 4;
  float* bc1      = (float*)p;          p += 2048 * 4;
  float* macc     = (float*)p;          p += 4 * 4;
  float* dinv     = (float*)p;          p += (size_t)NN * 4;
  float* dinv_src = (float*)p;          p += (size_t)(EE + 16) * 4;
  int*   cnt      = (int*)p;            p += (size_t)NN * 4;
  int*   offs     = (int*)p;            p += (size_t)(NN + 1) * 4 + 12;
  int*   cursor   = (int*)p;            p += (size_t)NN * 4;
  int*   srcs     = (int*)p;            p += (size_t)(EE + 16) * 4;

  unsigned short* Zbf = U;                       // NN x 512 (GINE agg out)
  unsigned short* Ybf = U + (size_t)NN * 512;    // NN x 1024 (MLP mid)
  unsigned short* Gbf = U + (size_t)NN * 1536;   // NN x 512 (MLP out, bf16)
  unsigned short* XLR = U;                       // NN x 2048 (GAT xl|xr, 2 heads)
  unsigned short* hw  = U;                       // NN x 512 (GCN h@W)

  hipMemsetAsync(cnt, 0, NN * sizeof(int), stream);
  hipMemsetAsync(cursor, 0, NN * sizeof(int), stream);
  hipMemsetAsync(macc, 0, 4 * sizeof(float), stream);

  k_edge_prep<<<128, 256, 0, stream>>>(dstArr, eattr, cnt, macc);
  k_scan<<<1, 256, 0, stream>>>(cnt, offs, dinv);
  k_fill<<<EE / 256, 256, 0, stream>>>(dstArr, srcArr, eattr, offs, dinv,
                                       cursor, srcs, ea4, dinv_src);

  // weight prep
  {
    k_transcast<<<dim3(1024 / 32, 512 / 32), 256, 0, stream>>>(gW1, 1024, w1t, 512, 1024);
    k_transcast<<<dim3(512 / 32, 1024 / 32), 256, 0, stream>>>(gW2, 512, w2t, 1024, 512);
    k_transcast<<<dim3(1024 / 32, 512 / 32), 256, 0, stream>>>(gatWl, 2048, wc0, 512, 1024);
    k_transcast<<<dim3(1024 / 32, 512 / 32), 256, 0, stream>>>(gatWr, 2048, wc0 + (size_t)1024 * 512, 512, 1024);
    k_transcast<<<dim3(1024 / 32, 512 / 32), 256, 0, stream>>>(gatWl + 1024, 2048, wc1, 512, 1024);
    k_transcast<<<dim3(1024 / 32, 512 / 32), 256, 0, stream>>>(gatWr + 1024, 2048, wc1 + (size_t)1024 * 512, 512, 1024);
    k_transcast<<<dim3(512 / 32, 512 / 32), 256, 0, stream>>>(gcn1W, 512, g1t, 512, 512);
    k_transcast<<<dim3(512 / 32, 512 / 32), 256, 0, stream>>>(gcn2W, 512, g2t, 512, 512);
    k_bcomb<<<16, 256, 0, stream>>>(gatbl, gatbr, bc0, bc1);
  }

  // input projection (bf16 only)
  k_proj<<<NN * DD / 256, 256, 0, stream>>>(x, Wproj, bproj, Xbf);

  // ---- layer 0: GINEConv + MLP + LN (MLP out bf16) ----
  k_gine_agg<<<NN / 4, 256, 0, stream>>>(Xbf, srcs, ea4, geW, geb, offs, Zbf);
  launch_bgemm(Zbf, w1t, gb1, Ybf, NN, 1024, 512, 1, stream);
  launch_bgemm(Ybf, w2t, gb2, Gbf, NN, 512, 1024, 0, stream);
  k_ln0<<<NN / 4, 256, 0, stream>>>(Gbf, Xbf, lgamma, lbeta, Xbf);

  // ---- layer 1: GATv2, two 2-head batches; per-(node,head) waves ----
  for (int b = 0; b < 2; ++b) {
    launch_bgemm(Xbf, b ? wc1 : wc0, b ? bc1 : bc0, XLR, NN, 2048, 512, 0, stream);
    k_gat_fused<<<NN / 2, 256, 0, stream>>>(XLR, srcs, offs, ea4, macc,
                                            gateW, gatatt, Hacc, Xbf, gatbias,
                                            lgamma + DD, lbeta + DD, b);
  }

  // ---- layers 2,3: GCN (aggregate + fused LN) ----
  launch_bgemm(Xbf, g1t, nullptr, hw, NN, 512, 512, 0, stream);
  k_gcn_ln<<<NN / 4, 256, 0, stream>>>(hw, srcs, offs, dinv_src, dinv, gcn1b,
                                       lgamma + 2 * DD, lbeta + 2 * DD, Xbf, nullptr);
  launch_bgemm(Xbf, g2t, nullptr, hw, NN, 512, 512, 0, stream);
  k_gcn_ln<<<NN / 4, 256, 0, stream>>>(hw, srcs, offs, dinv_src, dinv, gcn2b,
                                       lgamma + 3 * DD, lbeta + 3 * DD, Xbf, (float*)d_out);
}

// Round 10
// 525.943 us; speedup vs baseline: 1.1294x; 1.0012x over previous
//
#include <hip/hip_runtime.h>
#include <hip/hip_bf16.h>
#include <math.h>

#define NN   16384
#define EE   65536
#define DD   512
#define HH   4
#define FINN 7

typedef __attribute__((ext_vector_type(4))) float  floatx4;
typedef __attribute__((ext_vector_type(8))) float  floatx8;
typedef __attribute__((ext_vector_type(8))) short  shortx8;
typedef __attribute__((ext_vector_type(8))) unsigned short ushortx8;

// ---------------- helpers ----------------
__device__ inline float bf2f(unsigned short u) {
  return __uint_as_float(((unsigned)u) << 16);
}
__device__ inline unsigned short f2bf(float f) {
  unsigned u = __float_as_uint(f);
  unsigned r = (u + 0x7fffu + ((u >> 16) & 1u)) >> 16;
  return (unsigned short)r;
}
__device__ inline float wave_reduce_sum(float v) {
  #pragma unroll
  for (int off = 32; off > 0; off >>= 1) v += __shfl_down(v, off, 64);
  return v;
}
// wave64 sum via DPP: row_shr 1/2/4/8 (lane 15 of each 16-row = row sum),
// row_bcast15 (lane31=r0+r1, lane63=r2+r3), row_bcast31 (lane63=total).
// readlane(63) -> wave-uniform. All-lanes-active contexts only.
__device__ inline float wave_sum_u(float v) {
  v += __int_as_float(__builtin_amdgcn_update_dpp(0, __float_as_int(v), 0x111, 0xf, 0xf, true));
  v += __int_as_float(__builtin_amdgcn_update_dpp(0, __float_as_int(v), 0x112, 0xf, 0xf, true));
  v += __int_as_float(__builtin_amdgcn_update_dpp(0, __float_as_int(v), 0x114, 0xf, 0xf, true));
  v += __int_as_float(__builtin_amdgcn_update_dpp(0, __float_as_int(v), 0x118, 0xf, 0xf, true));
  v += __int_as_float(__builtin_amdgcn_update_dpp(0, __float_as_int(v), 0x142, 0xf, 0xf, true));
  v += __int_as_float(__builtin_amdgcn_update_dpp(0, __float_as_int(v), 0x143, 0xf, 0xf, true));
  return __int_as_float(__builtin_amdgcn_readlane(__float_as_int(v), 63));
}
__device__ inline void async16(const unsigned short* g, unsigned short* l) {
  __builtin_amdgcn_global_load_lds(
      (const __attribute__((address_space(1))) void*)g,
      (__attribute__((address_space(3))) void*)l, 16, 0, 0);
}

// ================= fused prep kernel (r16) =================
// All mutually-independent prep work in ONE launch: input projection,
// 8 weight transpose+casts, GAT bias combine, edge degree-count + attr mean.
// 11 serialized small launches (each 2-5us duration + drain) -> 1 dispatch.
// Jobs dispatch by blockIdx range; branches are block-uniform.
__device__ inline void transcast_body(const float* __restrict__ W, int ld,
                                      unsigned short* __restrict__ Wt,
                                      int K, int N, int bx, int by, int tidx,
                                      float (*tile)[33]) {
  int tx = tidx & 31, ty = tidx >> 5;
  #pragma unroll
  for (int i = 0; i < 32; i += 8)
    tile[ty + i][tx] = W[(size_t)(by * 32 + ty + i) * ld + bx * 32 + tx];
  __syncthreads();
  #pragma unroll
  for (int i = 0; i < 32; i += 8)
    Wt[(size_t)(bx * 32 + ty + i) * K + by * 32 + tx] = f2bf(tile[tx][ty + i]);
}

#define PREP_PROJ   32768            // NN*DD/256
#define PREP_TC1    (PREP_PROJ + 512)   // gW1  (32x16)
#define PREP_TC2    (PREP_TC1 + 512)    // gW2  (16x32)
#define PREP_TC3    (PREP_TC2 + 512)    // gatWl -> wc0
#define PREP_TC4    (PREP_TC3 + 512)    // gatWr -> wc0+
#define PREP_TC5    (PREP_TC4 + 512)    // gatWl+1024 -> wc1
#define PREP_TC6    (PREP_TC5 + 512)    // gatWr+1024 -> wc1+
#define PREP_TC7    (PREP_TC6 + 256)    // gcn1W -> g1t
#define PREP_TC8    (PREP_TC7 + 256)    // gcn2W -> g2t
#define PREP_BCOMB  (PREP_TC8 + 16)
#define PREP_EPREP  (PREP_BCOMB + 128)  // edge_prep: 128 blocks
#define PREP_TOTAL  PREP_EPREP

__global__ __launch_bounds__(256) void k_prep_all(
    const float* __restrict__ x, const float* __restrict__ Wproj,
    const float* __restrict__ bproj, unsigned short* __restrict__ Xbf,
    const float* __restrict__ gW1, unsigned short* __restrict__ w1t,
    const float* __restrict__ gW2, unsigned short* __restrict__ w2t,
    const float* __restrict__ gatWl, const float* __restrict__ gatWr,
    unsigned short* __restrict__ wc0, unsigned short* __restrict__ wc1,
    const float* __restrict__ gcn1W, unsigned short* __restrict__ g1t,
    const float* __restrict__ gcn2W, unsigned short* __restrict__ g2t,
    const float* __restrict__ gatbl, const float* __restrict__ gatbr,
    float* __restrict__ bc0, float* __restrict__ bc1,
    const int* __restrict__ dst, const float* __restrict__ eattr,
    int* __restrict__ cnt, float* __restrict__ macc) {
  __shared__ float tile[32][33];
  int bid = blockIdx.x;
  int tid = threadIdx.x;

  if (bid < PREP_PROJ) {
    // ---- input projection ----
    int gid = bid * 256 + tid;
    int n = gid >> 9, d = gid & 511;
    const float* xr = x + n * FINN;
    float acc = bproj[d];
    #pragma unroll
    for (int k = 0; k < FINN; ++k) acc = fmaf(xr[k], Wproj[k * DD + d], acc);
    Xbf[gid] = f2bf(fmaxf(acc, 0.f));
  } else if (bid < PREP_TC1) {
    int l = bid - PREP_PROJ;
    transcast_body(gW1, 1024, w1t, 512, 1024, l % 32, l / 32, tid, tile);
  } else if (bid < PREP_TC2) {
    int l = bid - PREP_TC1;
    transcast_body(gW2, 512, w2t, 1024, 512, l % 16, l / 16, tid, tile);
  } else if (bid < PREP_TC3) {
    int l = bid - PREP_TC2;
    transcast_body(gatWl, 2048, wc0, 512, 1024, l % 32, l / 32, tid, tile);
  } else if (bid < PREP_TC4) {
    int l = bid - PREP_TC3;
    transcast_body(gatWr, 2048, wc0 + (size_t)1024 * 512, 512, 1024, l % 32, l / 32, tid, tile);
  } else if (bid < PREP_TC5) {
    int l = bid - PREP_TC4;
    transcast_body(gatWl + 1024, 2048, wc1, 512, 1024, l % 32, l / 32, tid, tile);
  } else if (bid < PREP_TC6) {
    int l = bid - PREP_TC5;
    transcast_body(gatWr + 1024, 2048, wc1 + (size_t)1024 * 512, 512, 1024, l % 32, l / 32, tid, tile);
  } else if (bid < PREP_TC7) {
    int l = bid - PREP_TC6;
    transcast_body(gcn1W, 512, g1t, 512, 512, l % 16, l / 16, tid, tile);
  } else if (bid < PREP_TC8) {
    int l = bid - PREP_TC7;
    transcast_body(gcn2W, 512, g2t, 512, 512, l % 16, l / 16, tid, tile);
  } else if (bid < PREP_BCOMB) {
    int i = (bid - PREP_TC8) * 256 + tid;
    if (i < 4096) {
      int b = i >> 11, c = i & 2047;
      float v = (c < 1024) ? gatbl[b * 1024 + c] : gatbr[b * 1024 + c - 1024];
      (b ? bc1 : bc0)[c] = v;
    }
  } else {
    // ---- edge degree-count + edge_attr mean (grid-stride over 128 blocks) ----
    int lb = bid - PREP_BCOMB;
    int t0 = lb * 256 + tid;
    int stride = 128 * 256;
    float ax = 0.f, ay = 0.f, az = 0.f, aw = 0.f;
    for (int e = t0; e < EE; e += stride) {
      atomicAdd(&cnt[dst[e]], 1);
      float4 v = ((const float4*)eattr)[e];
      ax += v.x; ay += v.y; az += v.z; aw += v.w;
    }
    ax = wave_reduce_sum(ax); ay = wave_reduce_sum(ay);
    az = wave_reduce_sum(az); aw = wave_reduce_sum(aw);
    if ((tid & 63) == 0) {
      atomicAdd(&macc[0], ax); atomicAdd(&macc[1], ay);
      atomicAdd(&macc[2], az); atomicAdd(&macc[3], aw);
    }
  }
}

// ---------------- CSR build ----------------
// k_scan also emits dinv
__global__ void k_scan(const int* __restrict__ cnt, int* __restrict__ offs,
                       float* __restrict__ dinv) {
  __shared__ int sums[256];
  int t = threadIdx.x;
  const int chunk = NN / 256;
  int base = t * chunk;
  int s = 0;
  for (int i = 0; i < chunk; ++i) {
    int c = cnt[base + i];
    s += c;
    dinv[base + i] = rsqrtf((float)c + 1.0f);
  }
  sums[t] = s;
  __syncthreads();
  for (int off = 1; off < 256; off <<= 1) {
    int v = (t >= off) ? sums[t - off] : 0;
    __syncthreads();
    sums[t] += v;
    __syncthreads();
  }
  int run = (t == 0) ? 0 : sums[t - 1];
  for (int i = 0; i < chunk; ++i) {
    offs[base + i] = run;
    run += cnt[base + i];
  }
  if (t == 255) offs[NN] = run;
}

// k_fill materializes CSR-ordered src ids, edge attrs, and dinv[src]
__global__ void k_fill(const int* __restrict__ dst, const int* __restrict__ src,
                       const float* __restrict__ eattr, const int* __restrict__ offs,
                       const float* __restrict__ dinv,
                       int* __restrict__ cursor, int* __restrict__ srcs,
                       float4* __restrict__ ea4, float* __restrict__ dinv_src) {
  int e = blockIdx.x * 256 + threadIdx.x;
  if (e >= EE) return;
  int d = dst[e];
  int p = offs[d] + atomicAdd(&cursor[d], 1);
  int s = src[e];
  srcs[p] = s;
  ea4[p] = ((const float4*)eattr)[e];
  dinv_src[p] = dinv[s];
}

// ---------------- bf16 MFMA GEMM, XOR-swizzled LDS, XCD swizzle --------------------
// K is compile-time (r15): static trip count, hoisted stream pointers.
// LDS-staged coalesced epilogue (r14).
template <int K>
__global__ __launch_bounds__(256) void k_bgemm(
    const unsigned short* __restrict__ A, const unsigned short* __restrict__ Bt,
    const float* __restrict__ bias, unsigned short* __restrict__ Cout,
    int Nc, int act) {
  __shared__ unsigned short S[16384];   // 32KB: A(8192) | B(8192), then C tile
  unsigned short* As = S;
  unsigned short* Bs = S + 8192;
  const int tid = threadIdx.x;
  const int wv = tid >> 6;
  const int lane = tid & 63;
  // bijective XCD swizzle (nwg % 8 == 0 for all our launches)
  int gx = gridDim.x;
  int nwg = gx * gridDim.y;
  int wg = blockIdx.y * gx + blockIdx.x;
  if ((nwg & 7) == 0) {
    int cpx = nwg >> 3;
    wg = (wg & 7) * cpx + (wg >> 3);
  }
  const int row0 = (wg / gx) * 128;
  const int col0 = (wg % gx) * 128;
  const int wrow = (wv & 1) * 64;
  const int wcol = (wv >> 1) * 64;

  floatx4 acc[4][4];
  #pragma unroll
  for (int r = 0; r < 4; ++r)
    #pragma unroll
    for (int c = 0; c < 4; ++c)
      #pragma unroll
      for (int q = 0; q < 4; ++q) acc[r][c][q] = 0.f;

  const int lrow = lane >> 3;                       // 0..7 within segment
  const int lchunk = (lane & 7) ^ lrow;             // swizzled source k-chunk
  const int lk = lchunk * 8;                        // shorts

  // hoisted per-thread stream pointers (static after full unroll)
  const unsigned short* ap[4];
  const unsigned short* bp[4];
  #pragma unroll
  for (int i = 0; i < 4; ++i) {
    int seg = i * 4 + wv;
    int r = seg * 8 + lrow;
    ap[i] = A + (size_t)(row0 + r) * K + lk;
    bp[i] = Bt + (size_t)(col0 + r) * K + lk;
  }

  const int frow = lane & 15;
  const int fx = lane >> 4;
  const int fsw = lane & 7;

  #pragma unroll
  for (int kk = 0; kk < K / 64; ++kk) {
    #pragma unroll
    for (int i = 0; i < 4; ++i) {
      int seg = i * 4 + wv;
      async16(ap[i], &As[seg * 512]);
      async16(bp[i], &Bs[seg * 512]);
      ap[i] += 64;
      bp[i] += 64;
    }
    __syncthreads();
    #pragma unroll
    for (int s = 0; s < 2; ++s) {
      int ch = ((s * 4 + fx) ^ fsw) * 8;
      shortx8 af[4], bfr[4];
      #pragma unroll
      for (int r = 0; r < 4; ++r)
        af[r] = *(const shortx8*)&As[(wrow + r * 16 + frow) * 64 + ch];
      #pragma unroll
      for (int c = 0; c < 4; ++c)
        bfr[c] = *(const shortx8*)&Bs[(wcol + c * 16 + frow) * 64 + ch];
      #pragma unroll
      for (int r = 0; r < 4; ++r)
        #pragma unroll
        for (int c = 0; c < 4; ++c)
          acc[r][c] = __builtin_amdgcn_mfma_f32_16x16x32_bf16(af[r], bfr[c], acc[r][c], 0, 0, 0);
    }
    __syncthreads();
  }

  // ---- epilogue: bias/act, stage bf16 C tile in LDS, coalesced store ----
  #pragma unroll
  for (int r = 0; r < 4; ++r) {
    int lr0 = wrow + r * 16 + (lane >> 4) * 4;       // local row base
    #pragma unroll
    for (int c = 0; c < 4; ++c) {
      int lc = wcol + c * 16 + (lane & 15);          // local col
      float bv = bias ? bias[col0 + lc] : 0.f;
      #pragma unroll
      for (int q = 0; q < 4; ++q) {
        float v = acc[r][c][q] + bv;
        if (act) v = fmaxf(v, 0.f);
        S[(lr0 + q) * 128 + lc] = f2bf(v);
      }
    }
  }
  __syncthreads();
  #pragma unroll
  for (int i = 0; i < 8; ++i) {
    int idx = (i * 256 + tid) * 8;                   // short index in tile
    int lr = idx >> 7;
    int lc = idx & 127;
    *(ushortx8*)(Cout + (size_t)(row0 + lr) * Nc + col0 + lc) =
        *(const ushortx8*)&S[idx];
  }
}

// ------------- GINE aggregate (CSR-ordered srcs/ea4, no indirection) --------
__global__ void k_gine_agg(const unsigned short* __restrict__ hbf,
                           const int* __restrict__ srcs, const float4* __restrict__ ea4,
                           const float* __restrict__ geW, const float* __restrict__ geb,
                           const int* __restrict__ offs,
                           unsigned short* __restrict__ gbf) {
  int wave = (blockIdx.x * blockDim.x + threadIdx.x) >> 6;
  int lane = threadIdx.x & 63;
  if (wave >= NN) return;
  int n = wave;
  int cbase = lane * 8;
  floatx8 w0, w1, w2, w3, bb;
  #pragma unroll
  for (int j = 0; j < 8; ++j) {
    bb[j] = geb[cbase + j];
    w0[j] = geW[0 * DD + cbase + j];
    w1[j] = geW[1 * DD + cbase + j];
    w2[j] = geW[2 * DD + cbase + j];
    w3[j] = geW[3 * DD + cbase + j];
  }
  floatx8 acc = {0.f, 0.f, 0.f, 0.f, 0.f, 0.f, 0.f, 0.f};
  int beg = offs[n], end = offs[n + 1];
  int scur = srcs[beg];                    // padded array: srcs[EE] readable
  for (int p = beg; p < end; ++p) {
    int s = scur;
    scur = srcs[p + 1];                    // branchless one-ahead (padded)
    float4 ea = ea4[p];
    ushortx8 hv = *(const ushortx8*)(hbf + (size_t)s * DD + cbase);
    #pragma unroll
    for (int j = 0; j < 8; ++j) {
      float ev = bb[j];
      ev = fmaf(ea.x, w0[j], ev);
      ev = fmaf(ea.y, w1[j], ev);
      ev = fmaf(ea.z, w2[j], ev);
      ev = fmaf(ea.w, w3[j], ev);
      acc[j] += fmaxf(bf2f(hv[j]) + ev, 0.f);
    }
  }
  ushortx8 hn = *(const ushortx8*)(hbf + (size_t)n * DD + cbase);
  ushortx8 o;
  #pragma unroll
  for (int j = 0; j < 8; ++j) o[j] = f2bf(bf2f(hn[j]) + acc[j]);
  *(ushortx8*)(gbf + (size_t)n * DD + cbase) = o;
}

// -------- layer-0 LayerNorm ----------------
__global__ void k_ln0(const unsigned short* __restrict__ g, const unsigned short* __restrict__ res,
                      const float* __restrict__ gamma, const float* __restrict__ beta,
                      unsigned short* __restrict__ obf) {
  int wave = (blockIdx.x * blockDim.x + threadIdx.x) >> 6;
  int lane = threadIdx.x & 63;
  if (wave >= NN) return;
  int n = wave;
  int cbase = lane * 8;
  ushortx8 gv = *(const ushortx8*)(g + (size_t)n * DD + cbase);
  ushortx8 rv = *(const ushortx8*)(res + (size_t)n * DD + cbase);
  floatx8 v;
  float s = 0.f, sq = 0.f;
  #pragma unroll
  for (int j = 0; j < 8; ++j) {
    float t = fmaxf(bf2f(gv[j]), 0.f) + bf2f(rv[j]);
    v[j] = t;
    s += t; sq += t * t;
  }
  s = wave_sum_u(s);
  sq = wave_sum_u(sq);
  float mu = s * (1.f / DD);
  float var = sq * (1.f / DD) - mu * mu;
  float rstd = rsqrtf(var + 1e-5f);
  ushortx8 ob;
  #pragma unroll
  for (int j = 0; j < 8; ++j)
    ob[j] = f2bf(fmaf((v[j] - mu) * rstd, gamma[cbase + j], beta[cbase + j]));
  *(ushortx8*)(obf + (size_t)n * DD + cbase) = ob;
}

// ======== fused GATv2: per-(node,head) waves, DPP logit reduce ========
// Block = 256 threads = 4 waves = 2 nodes x 2 heads. Grid = NN/2.
__global__ __launch_bounds__(256) void k_gat_fused(
    const unsigned short* __restrict__ xlr,
    const int* __restrict__ srcs,
    const int* __restrict__ offs, const float4* __restrict__ ea4,
    const float* __restrict__ macc,
    const float* __restrict__ geW /*4x2048*/,
    const float* __restrict__ att /*4x512 (HxC)*/,
    unsigned short* __restrict__ Hacc, unsigned short* __restrict__ Xbf,
    const float* __restrict__ gbias,
    const float* __restrict__ gamma, const float* __restrict__ beta,
    int batch) {
  __shared__ float lsum[2][512];          // head-1 normalized sums, per node-slot
  int wv = threadIdx.x >> 6;              // 0..3
  int lane = threadIdx.x & 63;
  int slot = wv >> 1;                     // node slot in block (0,1)
  int h = wv & 1;                         // head within batch
  int n = blockIdx.x * 2 + slot;
  int c8 = lane * 8;
  int hoff = h * 512;                     // xl/xr slice offset (shorts)
  int hc = (2 * batch + h) * 512 + c8;    // channel base in 2048-wide weights
  const float invE = 1.f / EE;
  float meax = macc[0] * invE, meay = macc[1] * invE;
  float meaz = macc[2] * invE, meaw = macc[3] * invE;
  int beg = offs[n], end = offs[n + 1];

  floatx8 w0, w1, w2, w3, at, xr;
  #pragma unroll
  for (int j = 0; j < 8; ++j) {
    w0[j] = geW[0 * (HH * DD) + hc + j];
    w1[j] = geW[1 * (HH * DD) + hc + j];
    w2[j] = geW[2 * (HH * DD) + hc + j];
    w3[j] = geW[3 * (HH * DD) + hc + j];
    at[j] = att[hc + j];
  }
  {
    ushortx8 rr = *(const ushortx8*)(xlr + (size_t)n * 2048 + 1024 + hoff + c8);
    #pragma unroll
    for (int j = 0; j < 8; ++j) xr[j] = bf2f(rr[j]);
  }

  float l;
  floatx8 acc;
  // ---- self-loop (edge attr = mean) ----
  {
    ushortx8 a = *(const ushortx8*)(xlr + (size_t)n * 2048 + hoff + c8);
    float z = 0.f;
    #pragma unroll
    for (int j = 0; j < 8; ++j) {
      float t = bf2f(a[j]) + xr[j];
      t = fmaf(meax, w0[j], t);
      t = fmaf(meay, w1[j], t);
      t = fmaf(meaz, w2[j], t);
      t = fmaf(meaw, w3[j], t);
      t = (t >= 0.f) ? t : 0.2f * t;
      z = fmaf(t, at[j], z);
    }
    float w = __expf(wave_sum_u(z));
    l = w;
    #pragma unroll
    for (int j = 0; j < 8; ++j) acc[j] = w * bf2f(a[j]);
  }
  // ---- CSR edges (this head only; branchless one-ahead src) ----
  int scur = srcs[beg];                    // padded: srcs[EE] readable
  for (int p = beg; p < end; ++p) {
    int s = scur;
    scur = srcs[p + 1];
    float4 ea = ea4[p];
    ushortx8 a = *(const ushortx8*)(xlr + (size_t)s * 2048 + hoff + c8);
    float z = 0.f;
    #pragma unroll
    for (int j = 0; j < 8; ++j) {
      float t = bf2f(a[j]) + xr[j];
      t = fmaf(ea.x, w0[j], t);
      t = fmaf(ea.y, w1[j], t);
      t = fmaf(ea.z, w2[j], t);
      t = fmaf(ea.w, w3[j], t);
      t = (t >= 0.f) ? t : 0.2f * t;
      z = fmaf(t, at[j], z);
    }
    float w = __expf(wave_sum_u(z));
    l += w;
    #pragma unroll
    for (int j = 0; j < 8; ++j) acc[j] = fmaf(w, bf2f(a[j]), acc[j]);
  }

  float inv = 1.f / (l + 1e-16f);
  // head-1 waves publish their normalized sums; head-0 waves combine.
  if (h) {
    #pragma unroll
    for (int j = 0; j < 8; ++j) lsum[slot][c8 + j] = acc[j] * inv;
  }
  __syncthreads();
  if (h) return;

  floatx8 hsum;
  #pragma unroll
  for (int j = 0; j < 8; ++j) hsum[j] = acc[j] * inv + lsum[slot][c8 + j];

  unsigned short* hp = Hacc + (size_t)n * DD + c8;
  if (batch == 0) {
    ushortx8 o;
    #pragma unroll
    for (int j = 0; j < 8; ++j) o[j] = f2bf(hsum[j]);
    *(ushortx8*)hp = o;
    return;
  }
  // batch 1: mean over 4 heads, +bias, relu, +residual, LN, write bf16
  ushortx8 pv = *(const ushortx8*)hp;
  ushortx8 rv = *(const ushortx8*)(Xbf + (size_t)n * DD + c8);
  floatx8 v;
  float s = 0.f, sq = 0.f;
  #pragma unroll
  for (int j = 0; j < 8; ++j) {
    float g = (bf2f(pv[j]) + hsum[j]) * 0.25f + gbias[c8 + j];
    float val = fmaxf(g, 0.f) + bf2f(rv[j]);
    v[j] = val;
    s += val; sq += val * val;
  }
  s = wave_sum_u(s);
  sq = wave_sum_u(sq);
  float mu = s * (1.f / DD);
  float var = sq * (1.f / DD) - mu * mu;
  float rstd = rsqrtf(var + 1e-5f);
  ushortx8 ob;
  #pragma unroll
  for (int j = 0; j < 8; ++j)
    ob[j] = f2bf(fmaf((v[j] - mu) * rstd, gamma[c8 + j], beta[c8 + j]));
  *(ushortx8*)(Xbf + (size_t)n * DD + c8) = ob;
}

// ---------------- GCN aggregate + fused bias/relu/res/LN ----------------
__global__ void k_gcn_ln(const unsigned short* __restrict__ hw, const int* __restrict__ srcs,
                         const int* __restrict__ offs, const float* __restrict__ dinv_src,
                         const float* __restrict__ dinv, const float* __restrict__ bias,
                         const float* __restrict__ gamma, const float* __restrict__ beta,
                         unsigned short* __restrict__ Xbf, float* __restrict__ outf) {
  int wave = (blockIdx.x * blockDim.x + threadIdx.x) >> 6;
  int lane = threadIdx.x & 63;
  if (wave >= NN) return;
  int n = wave;
  int cbase = lane * 8;
  float dn = dinv[n];
  floatx8 acc;
  {
    float wself = dn * dn;
    ushortx8 hv = *(const ushortx8*)(hw + (size_t)n * DD + cbase);
    #pragma unroll
    for (int j = 0; j < 8; ++j) acc[j] = wself * bf2f(hv[j]);
  }
  int beg = offs[n], end = offs[n + 1];
  int scur = srcs[beg];                    // padded
  for (int p = beg; p < end; ++p) {
    int s = scur;
    scur = srcs[p + 1];
    float wgt = dinv_src[p] * dn;
    ushortx8 hv = *(const ushortx8*)(hw + (size_t)s * DD + cbase);
    #pragma unroll
    for (int j = 0; j < 8; ++j) acc[j] = fmaf(wgt, bf2f(hv[j]), acc[j]);
  }
  ushortx8 rv = *(const ushortx8*)(Xbf + (size_t)n * DD + cbase);
  floatx8 v;
  float s = 0.f, sq = 0.f;
  #pragma unroll
  for (int j = 0; j < 8; ++j) {
    float g = acc[j] + bias[cbase + j];
    float t = fmaxf(g, 0.f) + bf2f(rv[j]);
    v[j] = t;
    s += t; sq += t * t;
  }
  s = wave_sum_u(s);
  sq = wave_sum_u(sq);
  float mu = s * (1.f / DD);
  float var = sq * (1.f / DD) - mu * mu;
  float rstd = rsqrtf(var + 1e-5f);
  if (outf) {
    float4* o4 = (float4*)(outf + (size_t)n * DD + cbase);
    float4 oa, ob4;
    oa.x = fmaf((v[0] - mu) * rstd, gamma[cbase + 0], beta[cbase + 0]);
    oa.y = fmaf((v[1] - mu) * rstd, gamma[cbase + 1], beta[cbase + 1]);
    oa.z = fmaf((v[2] - mu) * rstd, gamma[cbase + 2], beta[cbase + 2]);
    oa.w = fmaf((v[3] - mu) * rstd, gamma[cbase + 3], beta[cbase + 3]);
    ob4.x = fmaf((v[4] - mu) * rstd, gamma[cbase + 4], beta[cbase + 4]);
    ob4.y = fmaf((v[5] - mu) * rstd, gamma[cbase + 5], beta[cbase + 5]);
    ob4.z = fmaf((v[6] - mu) * rstd, gamma[cbase + 6], beta[cbase + 6]);
    ob4.w = fmaf((v[7] - mu) * rstd, gamma[cbase + 7], beta[cbase + 7]);
    o4[0] = oa;
    o4[1] = ob4;
  } else {
    ushortx8 ob;
    #pragma unroll
    for (int j = 0; j < 8; ++j)
      ob[j] = f2bf(fmaf((v[j] - mu) * rstd, gamma[cbase + j], beta[cbase + j]));
    *(ushortx8*)(Xbf + (size_t)n * DD + cbase) = ob;
  }
}

// ---------------- host-side launcher ----------------
static void launch_bgemm(const unsigned short* A, const unsigned short* Bt,
                         const float* bias, unsigned short* C, int M, int Nc, int K,
                         int act, hipStream_t stream) {
  dim3 grid(Nc / 128, M / 128);
  if (K == 512)
    k_bgemm<512><<<grid, 256, 0, stream>>>(A, Bt, bias, C, Nc, act);
  else
    k_bgemm<1024><<<grid, 256, 0, stream>>>(A, Bt, bias, C, Nc, act);
}

extern "C" void kernel_launch(void* const* d_in, const int* in_sizes, int n_in,
                              void* d_out, int out_size, void* d_ws, size_t ws_size,
                              hipStream_t stream) {
  const float* x       = (const float*)d_in[0];
  const int*   eidx    = (const int*)d_in[1];
  const float* eattr   = (const float*)d_in[2];
  const float* Wproj   = (const float*)d_in[3];
  const float* bproj   = (const float*)d_in[4];
  const float* geW     = (const float*)d_in[5];
  const float* geb     = (const float*)d_in[6];
  const float* gW1     = (const float*)d_in[7];
  const float* gb1     = (const float*)d_in[8];
  const float* gW2     = (const float*)d_in[9];
  const float* gb2     = (const float*)d_in[10];
  const float* gatWl   = (const float*)d_in[11];
  const float* gatbl   = (const float*)d_in[12];
  const float* gatWr   = (const float*)d_in[13];
  const float* gatbr   = (const float*)d_in[14];
  const float* gateW   = (const float*)d_in[15];
  const float* gatatt  = (const float*)d_in[16];
  const float* gatbias = (const float*)d_in[17];
  const float* gcn1W   = (const float*)d_in[18];
  const float* gcn1b   = (const float*)d_in[19];
  const float* gcn2W   = (const float*)d_in[20];
  const float* gcn2b   = (const float*)d_in[21];
  const float* lgamma  = (const float*)d_in[22];
  const float* lbeta   = (const float*)d_in[23];
  const int* srcArr = eidx;
  const int* dstArr = eidx + EE;

  // ---- workspace carving (~105 MB) ----
  char* p = (char*)d_ws;
  unsigned short* Hacc = (unsigned short*)p; p += (size_t)NN * DD * 2;       // 16MB bf16 accum
  unsigned short* Xbf = (unsigned short*)p; p += (size_t)NN * DD * 2;        // 16MB
  unsigned short* U   = (unsigned short*)p; p += (size_t)NN * 2048 * 2;      // 64MB union
  unsigned short* w1t = (unsigned short*)p; p += (size_t)1024 * 512 * 2;
  unsigned short* w2t = (unsigned short*)p; p += (size_t)512 * 1024 * 2;
  unsigned short* wc0 = (unsigned short*)p; p += (size_t)2048 * 512 * 2;
  unsigned short* wc1 = (unsigned short*)p; p += (size_t)2048 * 512 * 2;
  unsigned short* g1t = (unsigned short*)p; p += (size_t)512 * 512 * 2;
  unsigned short* g2t = (unsigned short*)p; p += (size_t)512 * 512 * 2;
  float4* ea4     = (float4*)p;         p += (size_t)(EE + 4) * 16;      // 1MB (16B aligned)
  float* bc0      = (float*)p;          p += 2048 * 4;
  float* bc1      = (float*)p;          p += 2048 * 4;
  float* macc     = (float*)p;          p += 4 * 4;
  float* dinv     = (float*)p;          p += (size_t)NN * 4;
  float* dinv_src = (float*)p;          p += (size_t)(EE + 16) * 4;
  int*   cnt      = (int*)p;            p += (size_t)NN * 4;
  int*   offs     = (int*)p;            p += (size_t)(NN + 1) * 4 + 12;
  int*   cursor   = (int*)p;            p += (size_t)NN * 4;
  int*   srcs     = (int*)p;            p += (size_t)(EE + 16) * 4;

  unsigned short* Zbf = U;                       // NN x 512 (GINE agg out)
  unsigned short* Ybf = U + (size_t)NN * 512;    // NN x 1024 (MLP mid)
  unsigned short* Gbf = U + (size_t)NN * 1536;   // NN x 512 (MLP out, bf16)
  unsigned short* XLR = U;                       // NN x 2048 (GAT xl|xr, 2 heads)
  unsigned short* hw  = U;                       // NN x 512 (GCN h@W)

  hipMemsetAsync(cnt, 0, NN * sizeof(int), stream);
  hipMemsetAsync(cursor, 0, NN * sizeof(int), stream);
  hipMemsetAsync(macc, 0, 4 * sizeof(float), stream);

  // ---- fused prep: proj + 8 transcasts + bcomb + edge_prep in ONE launch ----
  k_prep_all<<<PREP_TOTAL, 256, 0, stream>>>(
      x, Wproj, bproj, Xbf,
      gW1, w1t, gW2, w2t, gatWl, gatWr, wc0, wc1,
      gcn1W, g1t, gcn2W, g2t,
      gatbl, gatbr, bc0, bc1,
      dstArr, eattr, cnt, macc);

  k_scan<<<1, 256, 0, stream>>>(cnt, offs, dinv);
  k_fill<<<EE / 256, 256, 0, stream>>>(dstArr, srcArr, eattr, offs, dinv,
                                       cursor, srcs, ea4, dinv_src);

  // ---- layer 0: GINEConv + MLP + LN (MLP out bf16) ----
  k_gine_agg<<<NN / 4, 256, 0, stream>>>(Xbf, srcs, ea4, geW, geb, offs, Zbf);
  launch_bgemm(Zbf, w1t, gb1, Ybf, NN, 1024, 512, 1, stream);
  launch_bgemm(Ybf, w2t, gb2, Gbf, NN, 512, 1024, 0, stream);
  k_ln0<<<NN / 4, 256, 0, stream>>>(Gbf, Xbf, lgamma, lbeta, Xbf);

  // ---- layer 1: GATv2, two 2-head batches; per-(node,head) waves ----
  for (int b = 0; b < 2; ++b) {
    launch_bgemm(Xbf, b ? wc1 : wc0, b ? bc1 : bc0, XLR, NN, 2048, 512, 0, stream);
    k_gat_fused<<<NN / 2, 256, 0, stream>>>(XLR, srcs, offs, ea4, macc,
                                            gateW, gatatt, Hacc, Xbf, gatbias,
                                            lgamma + DD, lbeta + DD, b);
  }

  // ---- layers 2,3: GCN (aggregate + fused LN) ----
  launch_bgemm(Xbf, g1t, nullptr, hw, NN, 512, 512, 0, stream);
  k_gcn_ln<<<NN / 4, 256, 0, stream>>>(hw, srcs, offs, dinv_src, dinv, gcn1b,
                                       lgamma + 2 * DD, lbeta + 2 * DD, Xbf, nullptr);
  launch_bgemm(Xbf, g2t, nullptr, hw, NN, 512, 512, 0, stream);
  k_gcn_ln<<<NN / 4, 256, 0, stream>>>(hw, srcs, offs, dinv_src, dinv, gcn2b,
                                       lgamma + 3 * DD, lbeta + 3 * DD, Xbf, (float*)d_out);
}

// Round 11
// 499.802 us; speedup vs baseline: 1.1885x; 1.0523x over previous
//
#include <hip/hip_runtime.h>
#include <hip/hip_bf16.h>
#include <math.h>

#define NN   16384
#define EE   65536
#define DD   512
#define HH   4
#define FINN 7

typedef __attribute__((ext_vector_type(4))) float  floatx4;
typedef __attribute__((ext_vector_type(8))) float  floatx8;
typedef __attribute__((ext_vector_type(8))) short  shortx8;
typedef __attribute__((ext_vector_type(8))) unsigned short ushortx8;

// ---------------- helpers ----------------
__device__ inline float bf2f(unsigned short u) {
  return __uint_as_float(((unsigned)u) << 16);
}
__device__ inline unsigned short f2bf(float f) {
  unsigned u = __float_as_uint(f);
  unsigned r = (u + 0x7fffu + ((u >> 16) & 1u)) >> 16;
  return (unsigned short)r;
}
__device__ inline float wave_reduce_sum(float v) {
  #pragma unroll
  for (int off = 32; off > 0; off >>= 1) v += __shfl_down(v, off, 64);
  return v;
}
// wave64 sum via DPP: row_shr 1/2/4/8 (lane 15 of each 16-row = row sum),
// row_bcast15 (lane31=r0+r1, lane63=r2+r3), row_bcast31 (lane63=total).
// readlane(63) -> wave-uniform. All-lanes-active contexts only.
__device__ inline float wave_sum_u(float v) {
  v += __int_as_float(__builtin_amdgcn_update_dpp(0, __float_as_int(v), 0x111, 0xf, 0xf, true));
  v += __int_as_float(__builtin_amdgcn_update_dpp(0, __float_as_int(v), 0x112, 0xf, 0xf, true));
  v += __int_as_float(__builtin_amdgcn_update_dpp(0, __float_as_int(v), 0x114, 0xf, 0xf, true));
  v += __int_as_float(__builtin_amdgcn_update_dpp(0, __float_as_int(v), 0x118, 0xf, 0xf, true));
  v += __int_as_float(__builtin_amdgcn_update_dpp(0, __float_as_int(v), 0x142, 0xf, 0xf, true));
  v += __int_as_float(__builtin_amdgcn_update_dpp(0, __float_as_int(v), 0x143, 0xf, 0xf, true));
  return __int_as_float(__builtin_amdgcn_readlane(__float_as_int(v), 63));
}
__device__ inline void async16(const unsigned short* g, unsigned short* l) {
  __builtin_amdgcn_global_load_lds(
      (const __attribute__((address_space(1))) void*)g,
      (__attribute__((address_space(3))) void*)l, 16, 0, 0);
}

// ================= fused prep kernel =================
// r17: proj section vectorized 8-wide (was 1 bf16/thread scalar store —
// the hidden 50us: 131k tiny latency-bound waves at 645 GB/s). Now thread
// = (node, 8ch): 7 broadcast x loads, 14 coalesced float4 W loads, 56 fma,
// one 16B ushortx8 store. 131k waves -> 16k.
__device__ inline void transcast_body(const float* __restrict__ W, int ld,
                                      unsigned short* __restrict__ Wt,
                                      int K, int N, int bx, int by, int tidx,
                                      float (*tile)[33]) {
  int tx = tidx & 31, ty = tidx >> 5;
  #pragma unroll
  for (int i = 0; i < 32; i += 8)
    tile[ty + i][tx] = W[(size_t)(by * 32 + ty + i) * ld + bx * 32 + tx];
  __syncthreads();
  #pragma unroll
  for (int i = 0; i < 32; i += 8)
    Wt[(size_t)(bx * 32 + ty + i) * K + by * 32 + tx] = f2bf(tile[tx][ty + i]);
}

#define PREP_PROJ   4096                // NN/4 (4 nodes per 256-thr block)
#define PREP_TC1    (PREP_PROJ + 512)   // gW1  (32x16)
#define PREP_TC2    (PREP_TC1 + 512)    // gW2  (16x32)
#define PREP_TC3    (PREP_TC2 + 512)    // gatWl -> wc0
#define PREP_TC4    (PREP_TC3 + 512)    // gatWr -> wc0+
#define PREP_TC5    (PREP_TC4 + 512)    // gatWl+1024 -> wc1
#define PREP_TC6    (PREP_TC5 + 512)    // gatWr+1024 -> wc1+
#define PREP_TC7    (PREP_TC6 + 256)    // gcn1W -> g1t
#define PREP_TC8    (PREP_TC7 + 256)    // gcn2W -> g2t
#define PREP_BCOMB  (PREP_TC8 + 16)
#define PREP_EPREP  (PREP_BCOMB + 128)  // edge_prep: 128 blocks
#define PREP_TOTAL  PREP_EPREP

__global__ __launch_bounds__(256) void k_prep_all(
    const float* __restrict__ x, const float* __restrict__ Wproj,
    const float* __restrict__ bproj, unsigned short* __restrict__ Xbf,
    const float* __restrict__ gW1, unsigned short* __restrict__ w1t,
    const float* __restrict__ gW2, unsigned short* __restrict__ w2t,
    const float* __restrict__ gatWl, const float* __restrict__ gatWr,
    unsigned short* __restrict__ wc0, unsigned short* __restrict__ wc1,
    const float* __restrict__ gcn1W, unsigned short* __restrict__ g1t,
    const float* __restrict__ gcn2W, unsigned short* __restrict__ g2t,
    const float* __restrict__ gatbl, const float* __restrict__ gatbr,
    float* __restrict__ bc0, float* __restrict__ bc1,
    const int* __restrict__ dst, const float* __restrict__ eattr,
    int* __restrict__ cnt, float* __restrict__ macc) {
  __shared__ float tile[32][33];
  int bid = blockIdx.x;
  int tid = threadIdx.x;

  if (bid < PREP_PROJ) {
    // ---- input projection, 8 channels/thread ----
    int gid = bid * 256 + tid;
    int n = gid >> 6;                 // 64 threads per node
    int c8 = (gid & 63) * 8;
    const float* xr = x + n * FINN;
    float xv[FINN];
    #pragma unroll
    for (int k = 0; k < FINN; ++k) xv[k] = xr[k];
    floatx8 acc;
    #pragma unroll
    for (int j = 0; j < 8; ++j) acc[j] = bproj[c8 + j];
    #pragma unroll
    for (int k = 0; k < FINN; ++k) {
      float4 wa = *(const float4*)(Wproj + k * DD + c8);
      float4 wb = *(const float4*)(Wproj + k * DD + c8 + 4);
      float xk = xv[k];
      acc[0] = fmaf(xk, wa.x, acc[0]);
      acc[1] = fmaf(xk, wa.y, acc[1]);
      acc[2] = fmaf(xk, wa.z, acc[2]);
      acc[3] = fmaf(xk, wa.w, acc[3]);
      acc[4] = fmaf(xk, wb.x, acc[4]);
      acc[5] = fmaf(xk, wb.y, acc[5]);
      acc[6] = fmaf(xk, wb.z, acc[6]);
      acc[7] = fmaf(xk, wb.w, acc[7]);
    }
    ushortx8 o;
    #pragma unroll
    for (int j = 0; j < 8; ++j) o[j] = f2bf(fmaxf(acc[j], 0.f));
    *(ushortx8*)(Xbf + (size_t)n * DD + c8) = o;
  } else if (bid < PREP_TC1) {
    int l = bid - PREP_PROJ;
    transcast_body(gW1, 1024, w1t, 512, 1024, l % 32, l / 32, tid, tile);
  } else if (bid < PREP_TC2) {
    int l = bid - PREP_TC1;
    transcast_body(gW2, 512, w2t, 1024, 512, l % 16, l / 16, tid, tile);
  } else if (bid < PREP_TC3) {
    int l = bid - PREP_TC2;
    transcast_body(gatWl, 2048, wc0, 512, 1024, l % 32, l / 32, tid, tile);
  } else if (bid < PREP_TC4) {
    int l = bid - PREP_TC3;
    transcast_body(gatWr, 2048, wc0 + (size_t)1024 * 512, 512, 1024, l % 32, l / 32, tid, tile);
  } else if (bid < PREP_TC5) {
    int l = bid - PREP_TC4;
    transcast_body(gatWl + 1024, 2048, wc1, 512, 1024, l % 32, l / 32, tid, tile);
  } else if (bid < PREP_TC6) {
    int l = bid - PREP_TC5;
    transcast_body(gatWr + 1024, 2048, wc1 + (size_t)1024 * 512, 512, 1024, l % 32, l / 32, tid, tile);
  } else if (bid < PREP_TC7) {
    int l = bid - PREP_TC6;
    transcast_body(gcn1W, 512, g1t, 512, 512, l % 16, l / 16, tid, tile);
  } else if (bid < PREP_TC8) {
    int l = bid - PREP_TC7;
    transcast_body(gcn2W, 512, g2t, 512, 512, l % 16, l / 16, tid, tile);
  } else if (bid < PREP_BCOMB) {
    int i = (bid - PREP_TC8) * 256 + tid;
    if (i < 4096) {
      int b = i >> 11, c = i & 2047;
      float v = (c < 1024) ? gatbl[b * 1024 + c] : gatbr[b * 1024 + c - 1024];
      (b ? bc1 : bc0)[c] = v;
    }
  } else {
    // ---- edge degree-count + edge_attr mean (grid-stride over 128 blocks) ----
    int lb = bid - PREP_BCOMB;
    int t0 = lb * 256 + tid;
    int stride = 128 * 256;
    float ax = 0.f, ay = 0.f, az = 0.f, aw = 0.f;
    for (int e = t0; e < EE; e += stride) {
      atomicAdd(&cnt[dst[e]], 1);
      float4 v = ((const float4*)eattr)[e];
      ax += v.x; ay += v.y; az += v.z; aw += v.w;
    }
    ax = wave_reduce_sum(ax); ay = wave_reduce_sum(ay);
    az = wave_reduce_sum(az); aw = wave_reduce_sum(aw);
    if ((tid & 63) == 0) {
      atomicAdd(&macc[0], ax); atomicAdd(&macc[1], ay);
      atomicAdd(&macc[2], az); atomicAdd(&macc[3], aw);
    }
  }
}

// ---------------- CSR build ----------------
// k_scan also emits dinv
__global__ void k_scan(const int* __restrict__ cnt, int* __restrict__ offs,
                       float* __restrict__ dinv) {
  __shared__ int sums[256];
  int t = threadIdx.x;
  const int chunk = NN / 256;
  int base = t * chunk;
  int s = 0;
  for (int i = 0; i < chunk; ++i) {
    int c = cnt[base + i];
    s += c;
    dinv[base + i] = rsqrtf((float)c + 1.0f);
  }
  sums[t] = s;
  __syncthreads();
  for (int off = 1; off < 256; off <<= 1) {
    int v = (t >= off) ? sums[t - off] : 0;
    __syncthreads();
    sums[t] += v;
    __syncthreads();
  }
  int run = (t == 0) ? 0 : sums[t - 1];
  for (int i = 0; i < chunk; ++i) {
    offs[base + i] = run;
    run += cnt[base + i];
  }
  if (t == 255) offs[NN] = run;
}

// k_fill materializes CSR-ordered src ids, edge attrs, and dinv[src]
__global__ void k_fill(const int* __restrict__ dst, const int* __restrict__ src,
                       const float* __restrict__ eattr, const int* __restrict__ offs,
                       const float* __restrict__ dinv,
                       int* __restrict__ cursor, int* __restrict__ srcs,
                       float4* __restrict__ ea4, float* __restrict__ dinv_src) {
  int e = blockIdx.x * 256 + threadIdx.x;
  if (e >= EE) return;
  int d = dst[e];
  int p = offs[d] + atomicAdd(&cursor[d], 1);
  int s = src[e];
  srcs[p] = s;
  ea4[p] = ((const float4*)eattr)[e];
  dinv_src[p] = dinv[s];
}

// ---------------- bf16 MFMA GEMM, XOR-swizzled LDS, XCD swizzle --------------------
// K is compile-time (r15): static trip count, hoisted stream pointers.
// LDS-staged coalesced epilogue (r14).
template <int K>
__global__ __launch_bounds__(256) void k_bgemm(
    const unsigned short* __restrict__ A, const unsigned short* __restrict__ Bt,
    const float* __restrict__ bias, unsigned short* __restrict__ Cout,
    int Nc, int act) {
  __shared__ unsigned short S[16384];   // 32KB: A(8192) | B(8192), then C tile
  unsigned short* As = S;
  unsigned short* Bs = S + 8192;
  const int tid = threadIdx.x;
  const int wv = tid >> 6;
  const int lane = tid & 63;
  // bijective XCD swizzle (nwg % 8 == 0 for all our launches)
  int gx = gridDim.x;
  int nwg = gx * gridDim.y;
  int wg = blockIdx.y * gx + blockIdx.x;
  if ((nwg & 7) == 0) {
    int cpx = nwg >> 3;
    wg = (wg & 7) * cpx + (wg >> 3);
  }
  const int row0 = (wg / gx) * 128;
  const int col0 = (wg % gx) * 128;
  const int wrow = (wv & 1) * 64;
  const int wcol = (wv >> 1) * 64;

  floatx4 acc[4][4];
  #pragma unroll
  for (int r = 0; r < 4; ++r)
    #pragma unroll
    for (int c = 0; c < 4; ++c)
      #pragma unroll
      for (int q = 0; q < 4; ++q) acc[r][c][q] = 0.f;

  const int lrow = lane >> 3;                       // 0..7 within segment
  const int lchunk = (lane & 7) ^ lrow;             // swizzled source k-chunk
  const int lk = lchunk * 8;                        // shorts

  // hoisted per-thread stream pointers (static after full unroll)
  const unsigned short* ap[4];
  const unsigned short* bp[4];
  #pragma unroll
  for (int i = 0; i < 4; ++i) {
    int seg = i * 4 + wv;
    int r = seg * 8 + lrow;
    ap[i] = A + (size_t)(row0 + r) * K + lk;
    bp[i] = Bt + (size_t)(col0 + r) * K + lk;
  }

  const int frow = lane & 15;
  const int fx = lane >> 4;
  const int fsw = lane & 7;

  #pragma unroll
  for (int kk = 0; kk < K / 64; ++kk) {
    #pragma unroll
    for (int i = 0; i < 4; ++i) {
      int seg = i * 4 + wv;
      async16(ap[i], &As[seg * 512]);
      async16(bp[i], &Bs[seg * 512]);
      ap[i] += 64;
      bp[i] += 64;
    }
    __syncthreads();
    #pragma unroll
    for (int s = 0; s < 2; ++s) {
      int ch = ((s * 4 + fx) ^ fsw) * 8;
      shortx8 af[4], bfr[4];
      #pragma unroll
      for (int r = 0; r < 4; ++r)
        af[r] = *(const shortx8*)&As[(wrow + r * 16 + frow) * 64 + ch];
      #pragma unroll
      for (int c = 0; c < 4; ++c)
        bfr[c] = *(const shortx8*)&Bs[(wcol + c * 16 + frow) * 64 + ch];
      #pragma unroll
      for (int r = 0; r < 4; ++r)
        #pragma unroll
        for (int c = 0; c < 4; ++c)
          acc[r][c] = __builtin_amdgcn_mfma_f32_16x16x32_bf16(af[r], bfr[c], acc[r][c], 0, 0, 0);
    }
    __syncthreads();
  }

  // ---- epilogue: bias/act, stage bf16 C tile in LDS, coalesced store ----
  #pragma unroll
  for (int r = 0; r < 4; ++r) {
    int lr0 = wrow + r * 16 + (lane >> 4) * 4;       // local row base
    #pragma unroll
    for (int c = 0; c < 4; ++c) {
      int lc = wcol + c * 16 + (lane & 15);          // local col
      float bv = bias ? bias[col0 + lc] : 0.f;
      #pragma unroll
      for (int q = 0; q < 4; ++q) {
        float v = acc[r][c][q] + bv;
        if (act) v = fmaxf(v, 0.f);
        S[(lr0 + q) * 128 + lc] = f2bf(v);
      }
    }
  }
  __syncthreads();
  #pragma unroll
  for (int i = 0; i < 8; ++i) {
    int idx = (i * 256 + tid) * 8;                   // short index in tile
    int lr = idx >> 7;
    int lc = idx & 127;
    *(ushortx8*)(Cout + (size_t)(row0 + lr) * Nc + col0 + lc) =
        *(const ushortx8*)&S[idx];
  }
}

// ------------- GINE aggregate (CSR-ordered srcs/ea4, no indirection) --------
__global__ void k_gine_agg(const unsigned short* __restrict__ hbf,
                           const int* __restrict__ srcs, const float4* __restrict__ ea4,
                           const float* __restrict__ geW, const float* __restrict__ geb,
                           const int* __restrict__ offs,
                           unsigned short* __restrict__ gbf) {
  int wave = (blockIdx.x * blockDim.x + threadIdx.x) >> 6;
  int lane = threadIdx.x & 63;
  if (wave >= NN) return;
  int n = wave;
  int cbase = lane * 8;
  floatx8 w0, w1, w2, w3, bb;
  #pragma unroll
  for (int j = 0; j < 8; ++j) {
    bb[j] = geb[cbase + j];
    w0[j] = geW[0 * DD + cbase + j];
    w1[j] = geW[1 * DD + cbase + j];
    w2[j] = geW[2 * DD + cbase + j];
    w3[j] = geW[3 * DD + cbase + j];
  }
  floatx8 acc = {0.f, 0.f, 0.f, 0.f, 0.f, 0.f, 0.f, 0.f};
  int beg = offs[n], end = offs[n + 1];
  int scur = srcs[beg];                    // padded array: srcs[EE] readable
  for (int p = beg; p < end; ++p) {
    int s = scur;
    scur = srcs[p + 1];                    // branchless one-ahead (padded)
    float4 ea = ea4[p];
    ushortx8 hv = *(const ushortx8*)(hbf + (size_t)s * DD + cbase);
    #pragma unroll
    for (int j = 0; j < 8; ++j) {
      float ev = bb[j];
      ev = fmaf(ea.x, w0[j], ev);
      ev = fmaf(ea.y, w1[j], ev);
      ev = fmaf(ea.z, w2[j], ev);
      ev = fmaf(ea.w, w3[j], ev);
      acc[j] += fmaxf(bf2f(hv[j]) + ev, 0.f);
    }
  }
  ushortx8 hn = *(const ushortx8*)(hbf + (size_t)n * DD + cbase);
  ushortx8 o;
  #pragma unroll
  for (int j = 0; j < 8; ++j) o[j] = f2bf(bf2f(hn[j]) + acc[j]);
  *(ushortx8*)(gbf + (size_t)n * DD + cbase) = o;
}

// -------- layer-0 LayerNorm ----------------
__global__ void k_ln0(const unsigned short* __restrict__ g, const unsigned short* __restrict__ res,
                      const float* __restrict__ gamma, const float* __restrict__ beta,
                      unsigned short* __restrict__ obf) {
  int wave = (blockIdx.x * blockDim.x + threadIdx.x) >> 6;
  int lane = threadIdx.x & 63;
  if (wave >= NN) return;
  int n = wave;
  int cbase = lane * 8;
  ushortx8 gv = *(const ushortx8*)(g + (size_t)n * DD + cbase);
  ushortx8 rv = *(const ushortx8*)(res + (size_t)n * DD + cbase);
  floatx8 v;
  float s = 0.f, sq = 0.f;
  #pragma unroll
  for (int j = 0; j < 8; ++j) {
    float t = fmaxf(bf2f(gv[j]), 0.f) + bf2f(rv[j]);
    v[j] = t;
    s += t; sq += t * t;
  }
  s = wave_sum_u(s);
  sq = wave_sum_u(sq);
  float mu = s * (1.f / DD);
  float var = sq * (1.f / DD) - mu * mu;
  float rstd = rsqrtf(var + 1e-5f);
  ushortx8 ob;
  #pragma unroll
  for (int j = 0; j < 8; ++j)
    ob[j] = f2bf(fmaf((v[j] - mu) * rstd, gamma[cbase + j], beta[cbase + j]));
  *(ushortx8*)(obf + (size_t)n * DD + cbase) = ob;
}

// ======== fused GATv2: per-(node,head) waves, DPP logit reduce ========
// Block = 256 threads = 4 waves = 2 nodes x 2 heads. Grid = NN/2.
__global__ __launch_bounds__(256) void k_gat_fused(
    const unsigned short* __restrict__ xlr,
    const int* __restrict__ srcs,
    const int* __restrict__ offs, const float4* __restrict__ ea4,
    const float* __restrict__ macc,
    const float* __restrict__ geW /*4x2048*/,
    const float* __restrict__ att /*4x512 (HxC)*/,
    unsigned short* __restrict__ Hacc, unsigned short* __restrict__ Xbf,
    const float* __restrict__ gbias,
    const float* __restrict__ gamma, const float* __restrict__ beta,
    int batch) {
  __shared__ float lsum[2][512];          // head-1 normalized sums, per node-slot
  int wv = threadIdx.x >> 6;              // 0..3
  int lane = threadIdx.x & 63;
  int slot = wv >> 1;                     // node slot in block (0,1)
  int h = wv & 1;                         // head within batch
  int n = blockIdx.x * 2 + slot;
  int c8 = lane * 8;
  int hoff = h * 512;                     // xl/xr slice offset (shorts)
  int hc = (2 * batch + h) * 512 + c8;    // channel base in 2048-wide weights
  const float invE = 1.f / EE;
  float meax = macc[0] * invE, meay = macc[1] * invE;
  float meaz = macc[2] * invE, meaw = macc[3] * invE;
  int beg = offs[n], end = offs[n + 1];

  floatx8 w0, w1, w2, w3, at, xr;
  #pragma unroll
  for (int j = 0; j < 8; ++j) {
    w0[j] = geW[0 * (HH * DD) + hc + j];
    w1[j] = geW[1 * (HH * DD) + hc + j];
    w2[j] = geW[2 * (HH * DD) + hc + j];
    w3[j] = geW[3 * (HH * DD) + hc + j];
    at[j] = att[hc + j];
  }
  {
    ushortx8 rr = *(const ushortx8*)(xlr + (size_t)n * 2048 + 1024 + hoff + c8);
    #pragma unroll
    for (int j = 0; j < 8; ++j) xr[j] = bf2f(rr[j]);
  }

  float l;
  floatx8 acc;
  // ---- self-loop (edge attr = mean) ----
  {
    ushortx8 a = *(const ushortx8*)(xlr + (size_t)n * 2048 + hoff + c8);
    float z = 0.f;
    #pragma unroll
    for (int j = 0; j < 8; ++j) {
      float t = bf2f(a[j]) + xr[j];
      t = fmaf(meax, w0[j], t);
      t = fmaf(meay, w1[j], t);
      t = fmaf(meaz, w2[j], t);
      t = fmaf(meaw, w3[j], t);
      t = (t >= 0.f) ? t : 0.2f * t;
      z = fmaf(t, at[j], z);
    }
    float w = __expf(wave_sum_u(z));
    l = w;
    #pragma unroll
    for (int j = 0; j < 8; ++j) acc[j] = w * bf2f(a[j]);
  }
  // ---- CSR edges (this head only; branchless one-ahead src) ----
  int scur = srcs[beg];                    // padded: srcs[EE] readable
  for (int p = beg; p < end; ++p) {
    int s = scur;
    scur = srcs[p + 1];
    float4 ea = ea4[p];
    ushortx8 a = *(const ushortx8*)(xlr + (size_t)s * 2048 + hoff + c8);
    float z = 0.f;
    #pragma unroll
    for (int j = 0; j < 8; ++j) {
      float t = bf2f(a[j]) + xr[j];
      t = fmaf(ea.x, w0[j], t);
      t = fmaf(ea.y, w1[j], t);
      t = fmaf(ea.z, w2[j], t);
      t = fmaf(ea.w, w3[j], t);
      t = (t >= 0.f) ? t : 0.2f * t;
      z = fmaf(t, at[j], z);
    }
    float w = __expf(wave_sum_u(z));
    l += w;
    #pragma unroll
    for (int j = 0; j < 8; ++j) acc[j] = fmaf(w, bf2f(a[j]), acc[j]);
  }

  float inv = 1.f / (l + 1e-16f);
  // head-1 waves publish their normalized sums; head-0 waves combine.
  if (h) {
    #pragma unroll
    for (int j = 0; j < 8; ++j) lsum[slot][c8 + j] = acc[j] * inv;
  }
  __syncthreads();
  if (h) return;

  floatx8 hsum;
  #pragma unroll
  for (int j = 0; j < 8; ++j) hsum[j] = acc[j] * inv + lsum[slot][c8 + j];

  unsigned short* hp = Hacc + (size_t)n * DD + c8;
  if (batch == 0) {
    ushortx8 o;
    #pragma unroll
    for (int j = 0; j < 8; ++j) o[j] = f2bf(hsum[j]);
    *(ushortx8*)hp = o;
    return;
  }
  // batch 1: mean over 4 heads, +bias, relu, +residual, LN, write bf16
  ushortx8 pv = *(const ushortx8*)hp;
  ushortx8 rv = *(const ushortx8*)(Xbf + (size_t)n * DD + c8);
  floatx8 v;
  float s = 0.f, sq = 0.f;
  #pragma unroll
  for (int j = 0; j < 8; ++j) {
    float g = (bf2f(pv[j]) + hsum[j]) * 0.25f + gbias[c8 + j];
    float val = fmaxf(g, 0.f) + bf2f(rv[j]);
    v[j] = val;
    s += val; sq += val * val;
  }
  s = wave_sum_u(s);
  sq = wave_sum_u(sq);
  float mu = s * (1.f / DD);
  float var = sq * (1.f / DD) - mu * mu;
  float rstd = rsqrtf(var + 1e-5f);
  ushortx8 ob;
  #pragma unroll
  for (int j = 0; j < 8; ++j)
    ob[j] = f2bf(fmaf((v[j] - mu) * rstd, gamma[c8 + j], beta[c8 + j]));
  *(ushortx8*)(Xbf + (size_t)n * DD + c8) = ob;
}

// ---------------- GCN aggregate + fused bias/relu/res/LN ----------------
__global__ void k_gcn_ln(const unsigned short* __restrict__ hw, const int* __restrict__ srcs,
                         const int* __restrict__ offs, const float* __restrict__ dinv_src,
                         const float* __restrict__ dinv, const float* __restrict__ bias,
                         const float* __restrict__ gamma, const float* __restrict__ beta,
                         unsigned short* __restrict__ Xbf, float* __restrict__ outf) {
  int wave = (blockIdx.x * blockDim.x + threadIdx.x) >> 6;
  int lane = threadIdx.x & 63;
  if (wave >= NN) return;
  int n = wave;
  int cbase = lane * 8;
  float dn = dinv[n];
  floatx8 acc;
  {
    float wself = dn * dn;
    ushortx8 hv = *(const ushortx8*)(hw + (size_t)n * DD + cbase);
    #pragma unroll
    for (int j = 0; j < 8; ++j) acc[j] = wself * bf2f(hv[j]);
  }
  int beg = offs[n], end = offs[n + 1];
  int scur = srcs[beg];                    // padded
  for (int p = beg; p < end; ++p) {
    int s = scur;
    scur = srcs[p + 1];
    float wgt = dinv_src[p] * dn;
    ushortx8 hv = *(const ushortx8*)(hw + (size_t)s * DD + cbase);
    #pragma unroll
    for (int j = 0; j < 8; ++j) acc[j] = fmaf(wgt, bf2f(hv[j]), acc[j]);
  }
  ushortx8 rv = *(const ushortx8*)(Xbf + (size_t)n * DD + cbase);
  floatx8 v;
  float s = 0.f, sq = 0.f;
  #pragma unroll
  for (int j = 0; j < 8; ++j) {
    float g = acc[j] + bias[cbase + j];
    float t = fmaxf(g, 0.f) + bf2f(rv[j]);
    v[j] = t;
    s += t; sq += t * t;
  }
  s = wave_sum_u(s);
  sq = wave_sum_u(sq);
  float mu = s * (1.f / DD);
  float var = sq * (1.f / DD) - mu * mu;
  float rstd = rsqrtf(var + 1e-5f);
  if (outf) {
    float4* o4 = (float4*)(outf + (size_t)n * DD + cbase);
    float4 oa, ob4;
    oa.x = fmaf((v[0] - mu) * rstd, gamma[cbase + 0], beta[cbase + 0]);
    oa.y = fmaf((v[1] - mu) * rstd, gamma[cbase + 1], beta[cbase + 1]);
    oa.z = fmaf((v[2] - mu) * rstd, gamma[cbase + 2], beta[cbase + 2]);
    oa.w = fmaf((v[3] - mu) * rstd, gamma[cbase + 3], beta[cbase + 3]);
    ob4.x = fmaf((v[4] - mu) * rstd, gamma[cbase + 4], beta[cbase + 4]);
    ob4.y = fmaf((v[5] - mu) * rstd, gamma[cbase + 5], beta[cbase + 5]);
    ob4.z = fmaf((v[6] - mu) * rstd, gamma[cbase + 6], beta[cbase + 6]);
    ob4.w = fmaf((v[7] - mu) * rstd, gamma[cbase + 7], beta[cbase + 7]);
    o4[0] = oa;
    o4[1] = ob4;
  } else {
    ushortx8 ob;
    #pragma unroll
    for (int j = 0; j < 8; ++j)
      ob[j] = f2bf(fmaf((v[j] - mu) * rstd, gamma[cbase + j], beta[cbase + j]));
    *(ushortx8*)(Xbf + (size_t)n * DD + cbase) = ob;
  }
}

// ---------------- host-side launcher ----------------
static void launch_bgemm(const unsigned short* A, const unsigned short* Bt,
                         const float* bias, unsigned short* C, int M, int Nc, int K,
                         int act, hipStream_t stream) {
  dim3 grid(Nc / 128, M / 128);
  if (K == 512)
    k_bgemm<512><<<grid, 256, 0, stream>>>(A, Bt, bias, C, Nc, act);
  else
    k_bgemm<1024><<<grid, 256, 0, stream>>>(A, Bt, bias, C, Nc, act);
}

extern "C" void kernel_launch(void* const* d_in, const int* in_sizes, int n_in,
                              void* d_out, int out_size, void* d_ws, size_t ws_size,
                              hipStream_t stream) {
  const float* x       = (const float*)d_in[0];
  const int*   eidx    = (const int*)d_in[1];
  const float* eattr   = (const float*)d_in[2];
  const float* Wproj   = (const float*)d_in[3];
  const float* bproj   = (const float*)d_in[4];
  const float* geW     = (const float*)d_in[5];
  const float* geb     = (const float*)d_in[6];
  const float* gW1     = (const float*)d_in[7];
  const float* gb1     = (const float*)d_in[8];
  const float* gW2     = (const float*)d_in[9];
  const float* gb2     = (const float*)d_in[10];
  const float* gatWl   = (const float*)d_in[11];
  const float* gatbl   = (const float*)d_in[12];
  const float* gatWr   = (const float*)d_in[13];
  const float* gatbr   = (const float*)d_in[14];
  const float* gateW   = (const float*)d_in[15];
  const float* gatatt  = (const float*)d_in[16];
  const float* gatbias = (const float*)d_in[17];
  const float* gcn1W   = (const float*)d_in[18];
  const float* gcn1b   = (const float*)d_in[19];
  const float* gcn2W   = (const float*)d_in[20];
  const float* gcn2b   = (const float*)d_in[21];
  const float* lgamma  = (const float*)d_in[22];
  const float* lbeta   = (const float*)d_in[23];
  const int* srcArr = eidx;
  const int* dstArr = eidx + EE;

  // ---- workspace carving (~105 MB) ----
  char* p = (char*)d_ws;
  unsigned short* Hacc = (unsigned short*)p; p += (size_t)NN * DD * 2;       // 16MB bf16 accum
  unsigned short* Xbf = (unsigned short*)p; p += (size_t)NN * DD * 2;        // 16MB
  unsigned short* U   = (unsigned short*)p; p += (size_t)NN * 2048 * 2;      // 64MB union
  unsigned short* w1t = (unsigned short*)p; p += (size_t)1024 * 512 * 2;
  unsigned short* w2t = (unsigned short*)p; p += (size_t)512 * 1024 * 2;
  unsigned short* wc0 = (unsigned short*)p; p += (size_t)2048 * 512 * 2;
  unsigned short* wc1 = (unsigned short*)p; p += (size_t)2048 * 512 * 2;
  unsigned short* g1t = (unsigned short*)p; p += (size_t)512 * 512 * 2;
  unsigned short* g2t = (unsigned short*)p; p += (size_t)512 * 512 * 2;
  float4* ea4     = (float4*)p;         p += (size_t)(EE + 4) * 16;      // 1MB (16B aligned)
  float* bc0      = (float*)p;          p += 2048 * 4;
  float* bc1      = (float*)p;          p += 2048 * 4;
  float* macc     = (float*)p;          p += 4 * 4;
  float* dinv     = (float*)p;          p += (size_t)NN * 4;
  float* dinv_src = (float*)p;          p += (size_t)(EE + 16) * 4;
  int*   cnt      = (int*)p;            p += (size_t)NN * 4;
  int*   offs     = (int*)p;            p += (size_t)(NN + 1) * 4 + 12;
  int*   cursor   = (int*)p;            p += (size_t)NN * 4;
  int*   srcs     = (int*)p;            p += (size_t)(EE + 16) * 4;

  unsigned short* Zbf = U;                       // NN x 512 (GINE agg out)
  unsigned short* Ybf = U + (size_t)NN * 512;    // NN x 1024 (MLP mid)
  unsigned short* Gbf = U + (size_t)NN * 1536;   // NN x 512 (MLP out, bf16)
  unsigned short* XLR = U;                       // NN x 2048 (GAT xl|xr, 2 heads)
  unsigned short* hw  = U;                       // NN x 512 (GCN h@W)

  hipMemsetAsync(cnt, 0, NN * sizeof(int), stream);
  hipMemsetAsync(cursor, 0, NN * sizeof(int), stream);
  hipMemsetAsync(macc, 0, 4 * sizeof(float), stream);

  // ---- fused prep: proj + 8 transcasts + bcomb + edge_prep in ONE launch ----
  k_prep_all<<<PREP_TOTAL, 256, 0, stream>>>(
      x, Wproj, bproj, Xbf,
      gW1, w1t, gW2, w2t, gatWl, gatWr, wc0, wc1,
      gcn1W, g1t, gcn2W, g2t,
      gatbl, gatbr, bc0, bc1,
      dstArr, eattr, cnt, macc);

  k_scan<<<1, 256, 0, stream>>>(cnt, offs, dinv);
  k_fill<<<EE / 256, 256, 0, stream>>>(dstArr, srcArr, eattr, offs, dinv,
                                       cursor, srcs, ea4, dinv_src);

  // ---- layer 0: GINEConv + MLP + LN (MLP out bf16) ----
  k_gine_agg<<<NN / 4, 256, 0, stream>>>(Xbf, srcs, ea4, geW, geb, offs, Zbf);
  launch_bgemm(Zbf, w1t, gb1, Ybf, NN, 1024, 512, 1, stream);
  launch_bgemm(Ybf, w2t, gb2, Gbf, NN, 512, 1024, 0, stream);
  k_ln0<<<NN / 4, 256, 0, stream>>>(Gbf, Xbf, lgamma, lbeta, Xbf);

  // ---- layer 1: GATv2, two 2-head batches; per-(node,head) waves ----
  for (int b = 0; b < 2; ++b) {
    launch_bgemm(Xbf, b ? wc1 : wc0, b ? bc1 : bc0, XLR, NN, 2048, 512, 0, stream);
    k_gat_fused<<<NN / 2, 256, 0, stream>>>(XLR, srcs, offs, ea4, macc,
                                            gateW, gatatt, Hacc, Xbf, gatbias,
                                            lgamma + DD, lbeta + DD, b);
  }

  // ---- layers 2,3: GCN (aggregate + fused LN) ----
  launch_bgemm(Xbf, g1t, nullptr, hw, NN, 512, 512, 0, stream);
  k_gcn_ln<<<NN / 4, 256, 0, stream>>>(hw, srcs, offs, dinv_src, dinv, gcn1b,
                                       lgamma + 2 * DD, lbeta + 2 * DD, Xbf, nullptr);
  launch_bgemm(Xbf, g2t, nullptr, hw, NN, 512, 512, 0, stream);
  k_gcn_ln<<<NN / 4, 256, 0, stream>>>(hw, srcs, offs, dinv_src, dinv, gcn2b,
                                       lgamma + 3 * DD, lbeta + 3 * DD, Xbf, (float*)d_out);
}